// Round 13
// baseline (4378.941 us; speedup 1.0000x reference)
//
#include <hip/hip_runtime.h>
#include <hip/hip_bf16.h>
#include <stdint.h>

#define Tn 512
#define Bn 64
#define Hn 512
#define LDP 520           // LDS row pitch (u16): 1040B
#define NWG 128
#define NTHR 512

typedef unsigned short u16;
typedef unsigned int u32;
typedef unsigned long long u64;
typedef __attribute__((ext_vector_type(8))) short bf16x8;
typedef __attribute__((ext_vector_type(4))) float f32x4;

// ws layout (bytes):
//   0     : ctr[2] barrier counters, one per batch-half, 64B apart
//   16384 : h0buf [2][Bn][Hn] bf16 (128KB)
//   147456: h1buf [2][Bn][Hn] bf16 (128KB)
//   278528: xbf [Tn][Bn][Hn] bf16 (32MB), if xok
#define HBUF_OFF 16384     // bytes

__device__ __forceinline__ u16 f2bf(float f) {
  u32 u = __float_as_uint(f);
  u = (u + 0x7FFFu + ((u >> 16) & 1u)) >> 16;   // RNE
  return (u16)u;
}
__device__ __forceinline__ float sigf(float x) { return 1.f / (1.f + __expf(-x)); }
__device__ __forceinline__ float mytanh(float x) {
  float e = __expf(2.f * x);
  return 1.f - 2.f / (e + 1.f);
}

// ---------- pre-kernel: x -> bf16 into ws, hx -> h parity-1 buffers ----------
extern "C" __global__ void __launch_bounds__(256)
lstm_prep(const float* __restrict__ x, const float* __restrict__ hx,
          u32* __restrict__ ws, int xok) {
  u16* h0buf = (u16*)((char*)ws + HBUF_OFF);
  u16* h1buf = h0buf + 2 * Bn * Hn;
  u16* xbf   = h1buf + 2 * Bn * Hn;
  const int gt = blockIdx.x * 256 + threadIdx.x;   // 0..524287
  if (xok) {
#pragma unroll
    for (int i = 0; i < 8; ++i) {
      const int c = gt + (i << 19);                // float4 chunk id, 4194304 total
      const float4 v = *(const float4*)(x + (size_t)c * 4);
      const u64 pk = (u64)((u32)f2bf(v.x) | ((u32)f2bf(v.y) << 16)) |
                     ((u64)((u32)f2bf(v.z) | ((u32)f2bf(v.w) << 16)) << 32);
      *(u64*)(xbf + (size_t)c * 4) = pk;
    }
  }
  if (gt < 32768) {
    const int e0 = 2 * gt;
    const int l = e0 >> 15;
    const int off = e0 & 32767;
    const u32 pk = (u32)f2bf(hx[e0]) | ((u32)f2bf(hx[e0 + 1]) << 16);
    *(u32*)((l ? h1buf : h0buf) + Bn * Hn + off) = pk;
  }
}

// ---------- main persistent cooperative kernel ----------
extern "C" __global__ void __launch_bounds__(NTHR, 2)
lstm_fused(const float* __restrict__ x, const float* __restrict__ hx,
           const float* __restrict__ cx, const float* __restrict__ Wih,
           const float* __restrict__ Whh, const float* __restrict__ bih,
           const float* __restrict__ bhh, float* __restrict__ out,
           u32* __restrict__ ws, int xok) {
  __shared__ u16 sh_inp[32 * LDP];
  __shared__ u16 sh_h[32 * LDP];

  const int wg = blockIdx.x;
  const int tid = threadIdx.x;
  const int layer = wg >> 6;        // 0..1
  const int rem = wg & 63;
  const int shalf = rem >> 5;       // batch half: samples 0-31 / 32-63
  const int cc = rem & 31;          // 16-column chunk
  const int wave = tid >> 6;        // 0..7
  const int lane = tid & 63;
  const int l15 = lane & 15;
  const int lhi = lane >> 4;
  const int mt = wave >> 1;         // 0..3 gate-row tile
  const int nt = wave & 1;          // 0..1 sample tile

  u32* ctr = ws;                                     // ctr[shalf] at ws[shalf*16]
  u16* h0buf = (u16*)((char*)ws + HBUF_OFF);
  u16* h1buf = h0buf + 2 * Bn * Hn;
  u16* xbf   = h1buf + 2 * Bn * Hn;
  u16* hbuf_my = layer ? h1buf : h0buf;

  // ---- weights -> registers. WG rows (64): j = col*4 + gate, col base cc*16 ----
  const int jrow = mt * 16 + l15;
  const int gateA = jrow & 3, colA = jrow >> 2;
  const int growA = gateA * Hn + cc * 16 + colA;
  const float* wihp = Wih + ((size_t)layer * 4 * Hn + growA) * Hn;
  const float* whhp = Whh + ((size_t)layer * 4 * Hn + growA) * Hn;
  bf16x8 wih_f[16], whh_f[16];
#pragma unroll
  for (int kt = 0; kt < 16; ++kt) {
    const int k0 = kt * 32 + lhi * 8;
    const float4 va0 = *(const float4*)(wihp + k0);
    const float4 va1 = *(const float4*)(wihp + k0 + 4);
    const float4 vb0 = *(const float4*)(whhp + k0);
    const float4 vb1 = *(const float4*)(whhp + k0 + 4);
    bf16x8 a, b;
    a[0]=(short)f2bf(va0.x); a[1]=(short)f2bf(va0.y); a[2]=(short)f2bf(va0.z); a[3]=(short)f2bf(va0.w);
    a[4]=(short)f2bf(va1.x); a[5]=(short)f2bf(va1.y); a[6]=(short)f2bf(va1.z); a[7]=(short)f2bf(va1.w);
    b[0]=(short)f2bf(vb0.x); b[1]=(short)f2bf(vb0.y); b[2]=(short)f2bf(vb0.z); b[3]=(short)f2bf(vb0.w);
    b[4]=(short)f2bf(vb1.x); b[5]=(short)f2bf(vb1.y); b[6]=(short)f2bf(vb1.z); b[7]=(short)f2bf(vb1.w);
    wih_f[kt] = a; whh_f[kt] = b;
  }

  // ---- elementwise lane mapping: acc reg r == gate r for (sampE, colE) ----
  const int colE = cc * 16 + mt * 4 + lhi;
  const int sampE = shalf * 32 + nt * 16 + l15;
  float bias[4];
#pragma unroll
  for (int r = 0; r < 4; ++r) {
    const int grow = r * Hn + cc * 16 + mt * 4 + lhi;
    bias[r] = bih[layer * 4 * Hn + grow] + bhh[layer * 4 * Hn + grow];
  }
  float c_cur = cx[((size_t)layer * Bn + sampE) * Hn + colE];

  // stage x(t) -> sh_inp (layer 0); plain loads, coherent via prep boundary;
  // xbf is read-only -> may cache in L2
  auto stage_x = [&](int t) {
    if (xok) {
      const u16* ip = xbf + ((size_t)t * Bn + shalf * 32) * Hn;
#pragma unroll
      for (int i = 0; i < 4; ++i) {
        const int chunk = tid + i * 512;             // 2048 chunks of 8 bf16
        const int row = chunk >> 6, c0 = (chunk & 63) * 8;
        const uint4 v = *(const uint4*)(ip + (size_t)row * Hn + c0);
        *(uint4*)(&sh_inp[row * LDP + c0]) = v;
      }
    } else {
      const float* xp = x + ((size_t)t * Bn + shalf * 32) * Hn;
#pragma unroll
      for (int i = 0; i < 8; ++i) {
        const int chunk = tid + i * 512;             // 4096 chunks of 4 floats
        const int row = chunk >> 7, c0 = (chunk & 127) * 4;
        const float4 v = *(const float4*)(xp + (size_t)row * Hn + c0);
        const u32 p0 = (u32)f2bf(v.x) | ((u32)f2bf(v.y) << 16);
        const u32 p1 = (u32)f2bf(v.z) | ((u32)f2bf(v.w) << 16);
        *(uint2*)(&sh_inp[row * LDP + c0]) = make_uint2(p0, p1);
      }
    }
  };
  if (layer == 0) stage_x(0);

  u32 ep = 0;
  for (int s = 0; s <= Tn; ++s) {
    const int t = layer ? s - 1 : s;
    const bool act = (t >= 0) && (t < Tn);

    if (act) {
      // restage h via relaxed agent atomic loads (LLC-direct, coherent with the
      // producers' agent write-through stores)
      const u16* hp = hbuf_my + (size_t)((t + 1) & 1) * Bn * Hn + (size_t)(shalf * 32) * Hn;
#pragma unroll
      for (int i = 0; i < 8; ++i) {
        const int chunk = tid + i * 512;             // 4096 chunks of 8B
        const int row = chunk >> 7, c0 = (chunk & 127) * 4;
        const u64 v = __hip_atomic_load((const u64*)(hp + (size_t)row * Hn + c0),
                                        __ATOMIC_RELAXED, __HIP_MEMORY_SCOPE_AGENT);
        *(u64*)(&sh_h[row * LDP + c0]) = v;
      }
      if (layer == 1) {
        const u16* ip = h0buf + (size_t)(t & 1) * Bn * Hn + (size_t)(shalf * 32) * Hn;
#pragma unroll
        for (int i = 0; i < 8; ++i) {
          const int chunk = tid + i * 512;
          const int row = chunk >> 7, c0 = (chunk & 127) * 4;
          const u64 v = __hip_atomic_load((const u64*)(ip + (size_t)row * Hn + c0),
                                          __ATOMIC_RELAXED, __HIP_MEMORY_SCOPE_AGENT);
          *(u64*)(&sh_inp[row * LDP + c0]) = v;
        }
      }
    }
    __syncthreads();

    float hn = 0.f, cn = 0.f;
    if (act) {
      f32x4 a0 = {0,0,0,0}, a1 = {0,0,0,0}, b0 = {0,0,0,0}, b1 = {0,0,0,0};
      const int brow = (nt * 16 + l15) * LDP;
#pragma unroll
      for (int kt = 0; kt < 16; kt += 2) {
        const bf16x8 bi0 = *(const bf16x8*)(&sh_inp[brow + kt * 32 + lhi * 8]);
        const bf16x8 bh0 = *(const bf16x8*)(&sh_h[brow + kt * 32 + lhi * 8]);
        const bf16x8 bi1 = *(const bf16x8*)(&sh_inp[brow + (kt + 1) * 32 + lhi * 8]);
        const bf16x8 bh1 = *(const bf16x8*)(&sh_h[brow + (kt + 1) * 32 + lhi * 8]);
        a0 = __builtin_amdgcn_mfma_f32_16x16x32_bf16(wih_f[kt], bi0, a0, 0, 0, 0);
        b0 = __builtin_amdgcn_mfma_f32_16x16x32_bf16(whh_f[kt], bh0, b0, 0, 0, 0);
        a1 = __builtin_amdgcn_mfma_f32_16x16x32_bf16(wih_f[kt + 1], bi1, a1, 0, 0, 0);
        b1 = __builtin_amdgcn_mfma_f32_16x16x32_bf16(whh_f[kt + 1], bh1, b1, 0, 0, 0);
      }
      const float gi = a0[0] + a1[0] + b0[0] + b1[0] + bias[0];
      const float gf = a0[1] + a1[1] + b0[1] + b1[1] + bias[1];
      const float gg = a0[2] + a1[2] + b0[2] + b1[2] + bias[2];
      const float go_ = a0[3] + a1[3] + b0[3] + b1[3] + bias[3];
      cn = sigf(gf) * c_cur + sigf(gi) * mytanh(gg);
      hn = sigf(go_) * mytanh(cn);
      c_cur = cn;

      // pack 4 cols (lhi 0..3, same sample) -> 8B agent store into h buffer
      const u32 hu = (u32)f2bf(hn);
      const u32 pair = hu | (__shfl_xor(hu, 16) << 16);
      const u32 hi2 = __shfl_xor(pair, 32);
      if (lhi == 0) {
        const u64 v8 = (u64)pair | ((u64)hi2 << 32);
        u16* wp = hbuf_my + (size_t)(t & 1) * Bn * Hn + (size_t)sampE * Hn + cc * 16 + mt * 4;
        __hip_atomic_store((u64*)wp, v8, __ATOMIC_RELAXED, __HIP_MEMORY_SCOPE_AGENT);
      }
    }
    // drain h stores, join WG, then one fire-and-forget add to the half counter
    asm volatile("s_waitcnt vmcnt(0)" ::: "memory");
    __syncthreads();
    ++ep;
    if (tid == 0)
      __hip_atomic_fetch_add(&ctr[shalf * 16], 1u,
                             __ATOMIC_RELAXED, __HIP_MEMORY_SCOPE_AGENT);

    // ---- shadow work (off the inter-WG critical path) ----
    if (act) {
      if (layer == 1)
        out[((size_t)t * Bn + sampE) * Hn + colE] = hn;
      if (t == Tn - 1) {
        out[(size_t)Tn * Bn * Hn + ((size_t)layer * Bn + sampE) * Hn + colE] = hn;
        out[(size_t)Tn * Bn * Hn + (size_t)2 * Bn * Hn + ((size_t)layer * Bn + sampE) * Hn + colE] = cn;
      }
    }
    if (layer == 0 && (s + 1) < Tn) stage_x(s + 1);

    if (s == Tn) break;   // nobody depends on the final barrier

    // ---- single-phase counter barrier: poll shared half counter ----
    // 64 WGs/half, each wave0 polls the SAME line (wave-coalesced loads)
    const u32 target = 64u * ep;
    if (wave == 0) {
      while (__hip_atomic_load(&ctr[shalf * 16], __ATOMIC_RELAXED,
                               __HIP_MEMORY_SCOPE_AGENT) < target)
        __builtin_amdgcn_s_sleep(1);
    }
    __syncthreads();   // join all waves to the detected barrier
    asm volatile("" ::: "memory");   // keep next restage loads after the poll
  }
}

extern "C" void kernel_launch(void* const* d_in, const int* in_sizes, int n_in,
                              void* d_out, int out_size, void* d_ws, size_t ws_size,
                              hipStream_t stream) {
  const float* x   = (const float*)d_in[0];
  const float* hx  = (const float*)d_in[1];
  const float* cx  = (const float*)d_in[2];
  const float* Wih = (const float*)d_in[3];
  const float* Whh = (const float*)d_in[4];
  const float* bih = (const float*)d_in[5];
  const float* bhh = (const float*)d_in[6];
  float* outp = (float*)d_out;
  u32* wsp = (u32*)d_ws;

  const size_t need = HBUF_OFF + (size_t)8 * Bn * Hn + (size_t)Tn * Bn * Hn * 2;
  int xok = (ws_size >= need) ? 1 : 0;

  hipMemsetAsync(d_ws, 0, HBUF_OFF, stream);   // zero barrier counters every call

  lstm_prep<<<dim3(2048), dim3(256), 0, stream>>>(x, hx, wsp, xok);

  void* args[] = {(void*)&x, (void*)&hx, (void*)&cx, (void*)&Wih, (void*)&Whh,
                  (void*)&bih, (void*)&bhh, (void*)&outp, (void*)&wsp, (void*)&xok};
  hipError_t e = hipLaunchCooperativeKernel((const void*)lstm_fused, dim3(NWG),
                                            dim3(NTHR), args, 0, stream);
  if (e != hipSuccess) {
    lstm_fused<<<dim3(NWG), dim3(NTHR), 0, stream>>>(x, hx, cx, Wih, Whh, bih, bhh, outp, wsp, xok);
  }
}

// Round 14
// 3108.594 us; speedup vs baseline: 1.4087x; 1.4087x over previous
//
#include <hip/hip_runtime.h>
#include <hip/hip_bf16.h>
#include <stdint.h>

#define Tn 512
#define Bn 64
#define Hn 512
#define LDP 520           // LDS row pitch (u16): 1040B
#define NWG 128
#define NTHR 512

typedef unsigned short u16;
typedef unsigned int u32;
typedef unsigned long long u64;
typedef __attribute__((ext_vector_type(8))) short bf16x8;
typedef __attribute__((ext_vector_type(4))) float f32x4;

// h-exchange: unit = u64 { low32: 2 cols bf16, high32: stamp = t+16 }
// buffer per (layer, shalf): [4 slot][32 samp][256 unit]  (256 KB)
// ws layout (bytes):
//   16384   : hexch, 4 buffers of 32768 u64  (1 MB)
//   1064960 : xbf [Tn][Bn][Hn] bf16 (32MB), if xok
#define HX_OFF   16384
#define XBF_OFF  1064960
#define SLOTU 8192          // u64 per slot (32*256)
#define BUFU  32768         // u64 per (layer,shalf) buffer

__device__ __forceinline__ u16 f2bf(float f) {
  u32 u = __float_as_uint(f);
  u = (u + 0x7FFFu + ((u >> 16) & 1u)) >> 16;   // RNE
  return (u16)u;
}
__device__ __forceinline__ float sigf(float x) { return 1.f / (1.f + __expf(-x)); }
__device__ __forceinline__ float mytanh(float x) {
  float e = __expf(2.f * x);
  return 1.f - 2.f / (e + 1.f);
}
__device__ __forceinline__ u64 ald(const u64* p) {
  return __hip_atomic_load(p, __ATOMIC_RELAXED, __HIP_MEMORY_SCOPE_AGENT);
}
__device__ __forceinline__ void ast(u64* p, u64 v) {
  __hip_atomic_store(p, v, __ATOMIC_RELAXED, __HIP_MEMORY_SCOPE_AGENT);
}

// ---------- pre-kernel: x -> bf16, hx -> stamped units in slot 3 ----------
extern "C" __global__ void __launch_bounds__(256)
lstm_prep(const float* __restrict__ x, const float* __restrict__ hx,
          u32* __restrict__ ws, int xok) {
  u64* hexch = (u64*)((char*)ws + HX_OFF);
  u16* xbf   = (u16*)((char*)ws + XBF_OFF);
  const int gt = blockIdx.x * 256 + threadIdx.x;   // 0..524287
  if (xok) {
#pragma unroll
    for (int i = 0; i < 8; ++i) {
      const int c = gt + (i << 19);                // float4 chunk id
      const float4 v = *(const float4*)(x + (size_t)c * 4);
      const u64 pk = (u64)((u32)f2bf(v.x) | ((u32)f2bf(v.y) << 16)) |
                     ((u64)((u32)f2bf(v.z) | ((u32)f2bf(v.w) << 16)) << 32);
      *(u64*)(xbf + (size_t)c * 4) = pk;
    }
  }
  if (gt < 32768) {
    const int f = gt;
    const int l = f >> 14;
    const int sh = (f >> 13) & 1;
    const int g = f & 8191;
    const int samp = g >> 8, unit = g & 255;
    const int b = sh * 32 + samp;
    const int c0 = unit * 2;
    const u32 d = (u32)f2bf(hx[((size_t)l * Bn + b) * Hn + c0]) |
                  ((u32)f2bf(hx[((size_t)l * Bn + b) * Hn + c0 + 1]) << 16);
    hexch[(size_t)(l * 2 + sh) * BUFU + 3 * SLOTU + samp * 256 + unit] =
        (u64)d | (15ULL << 32);                    // stamp = (-1)+16
  }
}

// ---------- main persistent cooperative kernel (barrier-free dataflow) ----------
extern "C" __global__ void __launch_bounds__(NTHR, 1)
lstm_fused(const float* __restrict__ x, const float* __restrict__ hx,
           const float* __restrict__ cx, const float* __restrict__ Wih,
           const float* __restrict__ Whh, const float* __restrict__ bih,
           const float* __restrict__ bhh, float* __restrict__ out,
           u32* __restrict__ ws, int xok) {
  __shared__ u16 sh_inp[32 * LDP];
  __shared__ u16 sh_h[32 * LDP];

  const int wg = blockIdx.x;
  const int tid = threadIdx.x;
  const int layer = wg >> 6;        // 0..1
  const int rem = wg & 63;
  const int shalf = rem >> 5;       // batch half
  const int cc = rem & 31;          // 16-column chunk
  const int wave = tid >> 6;
  const int lane = tid & 63;
  const int l15 = lane & 15;
  const int lhi = lane >> 4;
  const int mt = wave >> 1;         // gate-row tile
  const int nt = wave & 1;          // sample tile

  u64* hexch = (u64*)((char*)ws + HX_OFF);
  u16* xbf   = (u16*)((char*)ws + XBF_OFF);
  u64* hbuf_my = hexch + (size_t)(layer * 2 + shalf) * BUFU;
  u64* hbuf_l0 = hexch + (size_t)shalf * BUFU;             // (0, shalf)
  u64* hbuf_l1 = hexch + (size_t)(2 + shalf) * BUFU;       // (1, shalf)

  // ---- weights -> registers (R9 mapping, unchanged) ----
  const int jrow = mt * 16 + l15;
  const int gateA = jrow & 3, colA = jrow >> 2;
  const int growA = gateA * Hn + cc * 16 + colA;
  const float* wihp = Wih + ((size_t)layer * 4 * Hn + growA) * Hn;
  const float* whhp = Whh + ((size_t)layer * 4 * Hn + growA) * Hn;
  bf16x8 wih_f[16], whh_f[16];
#pragma unroll
  for (int kt = 0; kt < 16; ++kt) {
    const int k0 = kt * 32 + lhi * 8;
    const float4 va0 = *(const float4*)(wihp + k0);
    const float4 va1 = *(const float4*)(wihp + k0 + 4);
    const float4 vb0 = *(const float4*)(whhp + k0);
    const float4 vb1 = *(const float4*)(whhp + k0 + 4);
    bf16x8 a, b;
    a[0]=(short)f2bf(va0.x); a[1]=(short)f2bf(va0.y); a[2]=(short)f2bf(va0.z); a[3]=(short)f2bf(va0.w);
    a[4]=(short)f2bf(va1.x); a[5]=(short)f2bf(va1.y); a[6]=(short)f2bf(va1.z); a[7]=(short)f2bf(va1.w);
    b[0]=(short)f2bf(vb0.x); b[1]=(short)f2bf(vb0.y); b[2]=(short)f2bf(vb0.z); b[3]=(short)f2bf(vb0.w);
    b[4]=(short)f2bf(vb1.x); b[5]=(short)f2bf(vb1.y); b[6]=(short)f2bf(vb1.z); b[7]=(short)f2bf(vb1.w);
    wih_f[kt] = a; whh_f[kt] = b;
  }

  const int colE = cc * 16 + mt * 4 + lhi;
  const int sampE = shalf * 32 + nt * 16 + l15;
  const int sampL = nt * 16 + l15;                 // sample local to half
  float bias[4];
#pragma unroll
  for (int r = 0; r < 4; ++r) {
    const int grow = r * Hn + cc * 16 + mt * 4 + lhi;
    bias[r] = bih[layer * 4 * Hn + grow] + bhh[layer * 4 * Hn + grow];
  }
  float c_cur = cx[((size_t)layer * Bn + sampE) * Hn + colE];

  // per-thread restage mapping: 16 units, f = tid + i*512 -> (samp, unit)
  int rs_s[16], rs_u[16];
#pragma unroll
  for (int i = 0; i < 16; ++i) {
    const int f = tid + i * 512;
    rs_s[i] = f >> 8; rs_u[i] = f & 255;
  }

  // stage x(t) -> sh_inp (layer 0)
  auto stage_x = [&](int t) {
    if (xok) {
      const u16* ip = xbf + ((size_t)t * Bn + shalf * 32) * Hn;
#pragma unroll
      for (int i = 0; i < 4; ++i) {
        const int chunk = tid + i * 512;
        const int row = chunk >> 6, c0 = (chunk & 63) * 8;
        const uint4 v = *(const uint4*)(ip + (size_t)row * Hn + c0);
        *(uint4*)(&sh_inp[row * LDP + c0]) = v;
      }
    } else {
      const float* xp = x + ((size_t)t * Bn + shalf * 32) * Hn;
#pragma unroll
      for (int i = 0; i < 8; ++i) {
        const int chunk = tid + i * 512;
        const int row = chunk >> 7, c0 = (chunk & 127) * 4;
        const float4 v = *(const float4*)(xp + (size_t)row * Hn + c0);
        const u32 p0 = (u32)f2bf(v.x) | ((u32)f2bf(v.y) << 16);
        const u32 p1 = (u32)f2bf(v.z) | ((u32)f2bf(v.w) << 16);
        *(uint2*)(&sh_inp[row * LDP + c0]) = make_uint2(p0, p1);
      }
    }
  };
  if (layer == 0) stage_x(0);

  for (int t = 0; t < Tn; ++t) {
    // ---- L0 WAR throttle (wave0): L1 must have finished step t-4 ----
    if (layer == 0 && wave == 0 && t >= 4) {
      const u32 tgt = (u32)(t - 4 + 16);
      const u64* tp = hbuf_l1 + (size_t)((t - 4) & 3) * SLOTU + (lane & 31) * 8;
      while (true) {
        const u64 v = ald(tp);
        if (__all((int)((u32)(v >> 32) >= tgt))) break;
        __builtin_amdgcn_s_sleep(1);
      }
    }

    // ---- stamped restage: own h(t-1), slot (t-1)&3, stamp t+15 ----
    {
      u64* base = hbuf_my + (size_t)((t - 1) & 3) * SLOTU;
      u64 v[16];
#pragma unroll
      for (int i = 0; i < 16; ++i) v[i] = ald(base + rs_s[i] * 256 + rs_u[i]);
      const u32 tgt = (u32)(t + 15);
      while (true) {
        bool ok = true;
#pragma unroll
        for (int i = 0; i < 16; ++i)
          if ((u32)(v[i] >> 32) != tgt) { ok = false; v[i] = ald(base + rs_s[i] * 256 + rs_u[i]); }
        if (ok) break;
        __builtin_amdgcn_s_sleep(1);
      }
#pragma unroll
      for (int i = 0; i < 16; ++i)
        *(u32*)(&sh_h[rs_s[i] * LDP + rs_u[i] * 2]) = (u32)v[i];
    }
    // ---- L1: stamped restage of h0(t), slot t&3, stamp t+16 -> sh_inp ----
    if (layer == 1) {
      u64* base = hbuf_l0 + (size_t)(t & 3) * SLOTU;
      u64 v[16];
#pragma unroll
      for (int i = 0; i < 16; ++i) v[i] = ald(base + rs_s[i] * 256 + rs_u[i]);
      const u32 tgt = (u32)(t + 16);
      while (true) {
        bool ok = true;
#pragma unroll
        for (int i = 0; i < 16; ++i)
          if ((u32)(v[i] >> 32) != tgt) { ok = false; v[i] = ald(base + rs_s[i] * 256 + rs_u[i]); }
        if (ok) break;
        __builtin_amdgcn_s_sleep(1);
      }
#pragma unroll
      for (int i = 0; i < 16; ++i)
        *(u32*)(&sh_inp[rs_s[i] * LDP + rs_u[i] * 2]) = (u32)v[i];
    }
    __syncthreads();   // LDS staged; also joins wave0's throttle

    // ---- compute (bit-identical to R9) ----
    f32x4 a0 = {0,0,0,0}, a1 = {0,0,0,0}, b0 = {0,0,0,0}, b1 = {0,0,0,0};
    const int brow = (nt * 16 + l15) * LDP;
#pragma unroll
    for (int kt = 0; kt < 16; kt += 2) {
      const bf16x8 bi0 = *(const bf16x8*)(&sh_inp[brow + kt * 32 + lhi * 8]);
      const bf16x8 bh0 = *(const bf16x8*)(&sh_h[brow + kt * 32 + lhi * 8]);
      const bf16x8 bi1 = *(const bf16x8*)(&sh_inp[brow + (kt + 1) * 32 + lhi * 8]);
      const bf16x8 bh1 = *(const bf16x8*)(&sh_h[brow + (kt + 1) * 32 + lhi * 8]);
      a0 = __builtin_amdgcn_mfma_f32_16x16x32_bf16(wih_f[kt], bi0, a0, 0, 0, 0);
      b0 = __builtin_amdgcn_mfma_f32_16x16x32_bf16(whh_f[kt], bh0, b0, 0, 0, 0);
      a1 = __builtin_amdgcn_mfma_f32_16x16x32_bf16(wih_f[kt + 1], bi1, a1, 0, 0, 0);
      b1 = __builtin_amdgcn_mfma_f32_16x16x32_bf16(whh_f[kt + 1], bh1, b1, 0, 0, 0);
    }
    const float gi = a0[0] + a1[0] + b0[0] + b1[0] + bias[0];
    const float gf = a0[1] + a1[1] + b0[1] + b1[1] + bias[1];
    const float gg = a0[2] + a1[2] + b0[2] + b1[2] + bias[2];
    const float go_ = a0[3] + a1[3] + b0[3] + b1[3] + bias[3];
    const float cn = sigf(gf) * c_cur + sigf(gi) * mytanh(gg);
    const float hn = sigf(go_) * mytanh(cn);
    c_cur = cn;

    // ---- self-flagging h store: {2 cols bf16, stamp t+16} per u64 ----
    {
      const u32 hu = (u32)f2bf(hn);
      const u32 pair = hu | (__shfl_xor(hu, 16) << 16);   // lhi 0:{c0,c1} 2:{c2,c3}
      if (lhi == 0 || lhi == 2) {
        const int unit = cc * 8 + mt * 2 + (lhi >> 1);
        u64* wp = hbuf_my + (size_t)(t & 3) * SLOTU + sampL * 256 + unit;
        ast(wp, (u64)pair | ((u64)(u32)(t + 16) << 32));
      }
    }
    // ---- outputs (fire-and-forget) ----
    if (layer == 1)
      out[((size_t)t * Bn + sampE) * Hn + colE] = hn;
    if (t == Tn - 1) {
      out[(size_t)Tn * Bn * Hn + ((size_t)layer * Bn + sampE) * Hn + colE] = hn;
      out[(size_t)Tn * Bn * Hn + (size_t)2 * Bn * Hn + ((size_t)layer * Bn + sampE) * Hn + colE] = cn;
    }
    __syncthreads();   // all LDS reads done before next iteration's writes
    if (layer == 0 && (t + 1) < Tn) stage_x(t + 1);
  }
}

extern "C" void kernel_launch(void* const* d_in, const int* in_sizes, int n_in,
                              void* d_out, int out_size, void* d_ws, size_t ws_size,
                              hipStream_t stream) {
  const float* x   = (const float*)d_in[0];
  const float* hx  = (const float*)d_in[1];
  const float* cx  = (const float*)d_in[2];
  const float* Wih = (const float*)d_in[3];
  const float* Whh = (const float*)d_in[4];
  const float* bih = (const float*)d_in[5];
  const float* bhh = (const float*)d_in[6];
  float* outp = (float*)d_out;
  u32* wsp = (u32*)d_ws;

  const size_t need = (size_t)XBF_OFF + (size_t)Tn * Bn * Hn * 2;
  int xok = (ws_size >= need) ? 1 : 0;

  // zero header + entire stamped exchange region (stale stamps are poison)
  hipMemsetAsync(d_ws, 0, XBF_OFF, stream);

  lstm_prep<<<dim3(2048), dim3(256), 0, stream>>>(x, hx, wsp, xok);

  void* args[] = {(void*)&x, (void*)&hx, (void*)&cx, (void*)&Wih, (void*)&Whh,
                  (void*)&bih, (void*)&bhh, (void*)&outp, (void*)&wsp, (void*)&xok};
  hipError_t e = hipLaunchCooperativeKernel((const void*)lstm_fused, dim3(NWG),
                                            dim3(NTHR), args, 0, stream);
  if (e != hipSuccess) {
    lstm_fused<<<dim3(NWG), dim3(NTHR), 0, stream>>>(x, hx, cx, Wih, Whh, bih, bhh, outp, wsp, xok);
  }
}

// Round 15
// 2102.422 us; speedup vs baseline: 2.0828x; 1.4786x over previous
//
#include <hip/hip_runtime.h>
#include <hip/hip_bf16.h>
#include <stdint.h>

#define Tn 512
#define Bn 64
#define Hn 512
#define LDP 520           // LDS row pitch (u16): 1040B
#define NWG 128
#define NTHR 512
#define BnHn (Bn * Hn)    // 32768 elems per (slot, layer) plane

typedef unsigned short u16;
typedef unsigned int u32;
typedef unsigned long long u64;
typedef __attribute__((ext_vector_type(8))) short bf16x8;
typedef __attribute__((ext_vector_type(4))) float f32x4;

// ws layout (bytes):
//   0     : slots[128] (one 64B line per WG)   8KB
//   8192  : go[128]    (one 64B line per WG)   8KB
//   16384 : hist [nslot][2 layer][Bn][Hn] bf16  (nslot = 513 if histok else 2)
//   after : xbf [Tn][Bn][Hn] bf16 (32MB), if xok
#define GO_OFF   2048      // u32 index
#define HIST_OFF 16384     // bytes

__device__ __forceinline__ u16 f2bf(float f) {
  u32 u = __float_as_uint(f);
  u = (u + 0x7FFFu + ((u >> 16) & 1u)) >> 16;   // RNE
  return (u16)u;
}
__device__ __forceinline__ float sigf(float x) { return 1.f / (1.f + __expf(-x)); }
__device__ __forceinline__ float mytanh(float x) {
  float e = __expf(2.f * x);
  return 1.f - 2.f / (e + 1.f);
}

// ---------- pre-kernel: x -> bf16, hx -> hist init slot ----------
extern "C" __global__ void __launch_bounds__(256)
lstm_prep(const float* __restrict__ x, const float* __restrict__ hx,
          u32* __restrict__ ws, int xok, int histok) {
  u16* hist = (u16*)((char*)ws + HIST_OFF);
  u16* xbf  = hist + (size_t)(histok ? 513 : 2) * 2 * BnHn;
  const int slot_init = histok ? 512 : 1;
  const int gt = blockIdx.x * 256 + threadIdx.x;   // 0..524287
  if (xok) {
#pragma unroll
    for (int i = 0; i < 8; ++i) {
      const int c = gt + (i << 19);                // float4 chunk id, 4194304 total
      const float4 v = *(const float4*)(x + (size_t)c * 4);
      const u64 pk = (u64)((u32)f2bf(v.x) | ((u32)f2bf(v.y) << 16)) |
                     ((u64)((u32)f2bf(v.z) | ((u32)f2bf(v.w) << 16)) << 32);
      *(u64*)(xbf + (size_t)c * 4) = pk;
    }
  }
  if (gt < 32768) {
    const int e0 = 2 * gt;
    const int l = e0 >> 15;
    const int off = e0 & 32767;
    const u32 pk = (u32)f2bf(hx[e0]) | ((u32)f2bf(hx[e0 + 1]) << 16);
    *(u32*)(hist + ((size_t)slot_init * 2 + l) * BnHn + off) = pk;
  }
}

// ---------- main persistent cooperative kernel ----------
extern "C" __global__ void __launch_bounds__(NTHR, 2)
lstm_fused(const float* __restrict__ x, const float* __restrict__ hx,
           const float* __restrict__ cx, const float* __restrict__ Wih,
           const float* __restrict__ Whh, const float* __restrict__ bih,
           const float* __restrict__ bhh, float* __restrict__ out,
           u32* __restrict__ ws, int xok, int histok) {
  __shared__ u16 sh_inp[32 * LDP];
  __shared__ u16 sh_h[32 * LDP];
  __shared__ u32 sh_flag;

  // one-time L1/L2 invalidate: drop any lines poisoned (0xAA) between launches
  __builtin_amdgcn_fence(__ATOMIC_ACQUIRE, "agent");

  const int wg = blockIdx.x;
  const int tid = threadIdx.x;
  const int layer = wg >> 6;        // 0..1
  const int rem = wg & 63;
  const int shalf = rem >> 5;       // batch half: samples 0-31 / 32-63
  const int cc = rem & 31;          // 16-column chunk
  const int wave = tid >> 6;        // 0..7
  const int lane = tid & 63;
  const int l15 = lane & 15;
  const int lhi = lane >> 4;
  const int mt = wave >> 1;         // 0..3 gate-row tile
  const int nt = wave & 1;          // 0..1 sample tile
  const bool leader_wg = (layer == 0) && (cc == 0);  // wg == shalf*32

  u32* slots = ws;                                   // slot[w] = slots[w*16]
  u32* gof   = ws + GO_OFF;                          // go[w]   = gof[w*16]
  u16* hist  = (u16*)((char*)ws + HIST_OFF);
  u16* xbf   = hist + (size_t)(histok ? 513 : 2) * 2 * BnHn;

  if (tid == 0) sh_flag = 0;

  // ---- weights -> registers. WG rows (64): j = col*4 + gate, col base cc*16 ----
  const int jrow = mt * 16 + l15;
  const int gateA = jrow & 3, colA = jrow >> 2;
  const int growA = gateA * Hn + cc * 16 + colA;
  const float* wihp = Wih + ((size_t)layer * 4 * Hn + growA) * Hn;
  const float* whhp = Whh + ((size_t)layer * 4 * Hn + growA) * Hn;
  bf16x8 wih_f[16], whh_f[16];
#pragma unroll
  for (int kt = 0; kt < 16; ++kt) {
    const int k0 = kt * 32 + lhi * 8;
    const float4 va0 = *(const float4*)(wihp + k0);
    const float4 va1 = *(const float4*)(wihp + k0 + 4);
    const float4 vb0 = *(const float4*)(whhp + k0);
    const float4 vb1 = *(const float4*)(whhp + k0 + 4);
    bf16x8 a, b;
    a[0]=(short)f2bf(va0.x); a[1]=(short)f2bf(va0.y); a[2]=(short)f2bf(va0.z); a[3]=(short)f2bf(va0.w);
    a[4]=(short)f2bf(va1.x); a[5]=(short)f2bf(va1.y); a[6]=(short)f2bf(va1.z); a[7]=(short)f2bf(va1.w);
    b[0]=(short)f2bf(vb0.x); b[1]=(short)f2bf(vb0.y); b[2]=(short)f2bf(vb0.z); b[3]=(short)f2bf(vb0.w);
    b[4]=(short)f2bf(vb1.x); b[5]=(short)f2bf(vb1.y); b[6]=(short)f2bf(vb1.z); b[7]=(short)f2bf(vb1.w);
    wih_f[kt] = a; whh_f[kt] = b;
  }

  // ---- elementwise lane mapping: acc reg r == gate r for (sampE, colE) ----
  const int colE = cc * 16 + mt * 4 + lhi;
  const int sampE = shalf * 32 + nt * 16 + l15;
  float bias[4];
#pragma unroll
  for (int r = 0; r < 4; ++r) {
    const int grow = r * Hn + cc * 16 + mt * 4 + lhi;
    bias[r] = bih[layer * 4 * Hn + grow] + bhh[layer * 4 * Hn + grow];
  }
  float c_cur = cx[((size_t)layer * Bn + sampE) * Hn + colE];

  // stage x(t) -> sh_inp (layer 0); plain loads, coherent via prep boundary
  auto stage_x = [&](int t) {
    if (xok) {
      const u16* ip = xbf + ((size_t)t * Bn + shalf * 32) * Hn;
#pragma unroll
      for (int i = 0; i < 4; ++i) {
        const int chunk = tid + i * 512;             // 2048 chunks of 8 bf16
        const int row = chunk >> 6, c0 = (chunk & 63) * 8;
        const uint4 v = *(const uint4*)(ip + (size_t)row * Hn + c0);
        *(uint4*)(&sh_inp[row * LDP + c0]) = v;
      }
    } else {
      const float* xp = x + ((size_t)t * Bn + shalf * 32) * Hn;
#pragma unroll
      for (int i = 0; i < 8; ++i) {
        const int chunk = tid + i * 512;             // 4096 chunks of 4 floats
        const int row = chunk >> 7, c0 = (chunk & 127) * 4;
        const float4 v = *(const float4*)(xp + (size_t)row * Hn + c0);
        const u32 p0 = (u32)f2bf(v.x) | ((u32)f2bf(v.y) << 16);
        const u32 p1 = (u32)f2bf(v.z) | ((u32)f2bf(v.w) << 16);
        *(uint2*)(&sh_inp[row * LDP + c0]) = make_uint2(p0, p1);
      }
    }
  };
  if (layer == 0) stage_x(0);

  u32 ep = 0;
  for (int s = 0; s <= Tn; ++s) {
    const int t = layer ? s - 1 : s;
    const bool act = (t >= 0) && (t < Tn);

    if (act) {
      // slot indices: histok -> monotonic (never-reused addresses, L2-cacheable);
      // fallback -> parity-2 ring (R9 semantics, agent loads)
      const int slotR = histok ? ((t == 0) ? 512 : (t - 1)) : ((t - 1) & 1);
      const u16* hp = hist + ((size_t)slotR * 2 + layer) * BnHn + (size_t)(shalf * 32) * Hn;
      if (histok) {
#pragma unroll
        for (int i = 0; i < 4; ++i) {
          const int chunk = tid + i * 512;           // 2048 chunks of 16B
          const int row = chunk >> 6, c0 = (chunk & 63) * 8;
          const uint4 v = *(const uint4*)(hp + (size_t)row * Hn + c0);
          *(uint4*)(&sh_h[row * LDP + c0]) = v;
        }
      } else {
#pragma unroll
        for (int i = 0; i < 8; ++i) {
          const int chunk = tid + i * 512;           // 4096 chunks of 8B
          const int row = chunk >> 7, c0 = (chunk & 127) * 4;
          const u64 v = __hip_atomic_load((const u64*)(hp + (size_t)row * Hn + c0),
                                          __ATOMIC_RELAXED, __HIP_MEMORY_SCOPE_AGENT);
          *(u64*)(&sh_h[row * LDP + c0]) = v;
        }
      }
      if (layer == 1) {
        const int slotI = histok ? t : (t & 1);
        const u16* ip = hist + ((size_t)slotI * 2 + 0) * BnHn + (size_t)(shalf * 32) * Hn;
        if (histok) {
#pragma unroll
          for (int i = 0; i < 4; ++i) {
            const int chunk = tid + i * 512;
            const int row = chunk >> 6, c0 = (chunk & 63) * 8;
            const uint4 v = *(const uint4*)(ip + (size_t)row * Hn + c0);
            *(uint4*)(&sh_inp[row * LDP + c0]) = v;
          }
        } else {
#pragma unroll
          for (int i = 0; i < 8; ++i) {
            const int chunk = tid + i * 512;
            const int row = chunk >> 7, c0 = (chunk & 127) * 4;
            const u64 v = __hip_atomic_load((const u64*)(ip + (size_t)row * Hn + c0),
                                            __ATOMIC_RELAXED, __HIP_MEMORY_SCOPE_AGENT);
            *(u64*)(&sh_inp[row * LDP + c0]) = v;
          }
        }
      }
    }
    __syncthreads();

    float hn = 0.f, cn = 0.f;
    if (act) {
      f32x4 a0 = {0,0,0,0}, a1 = {0,0,0,0}, b0 = {0,0,0,0}, b1 = {0,0,0,0};
      const int brow = (nt * 16 + l15) * LDP;
#pragma unroll
      for (int kt = 0; kt < 16; kt += 2) {
        const bf16x8 bi0 = *(const bf16x8*)(&sh_inp[brow + kt * 32 + lhi * 8]);
        const bf16x8 bh0 = *(const bf16x8*)(&sh_h[brow + kt * 32 + lhi * 8]);
        const bf16x8 bi1 = *(const bf16x8*)(&sh_inp[brow + (kt + 1) * 32 + lhi * 8]);
        const bf16x8 bh1 = *(const bf16x8*)(&sh_h[brow + (kt + 1) * 32 + lhi * 8]);
        a0 = __builtin_amdgcn_mfma_f32_16x16x32_bf16(wih_f[kt], bi0, a0, 0, 0, 0);
        b0 = __builtin_amdgcn_mfma_f32_16x16x32_bf16(whh_f[kt], bh0, b0, 0, 0, 0);
        a1 = __builtin_amdgcn_mfma_f32_16x16x32_bf16(wih_f[kt + 1], bi1, a1, 0, 0, 0);
        b1 = __builtin_amdgcn_mfma_f32_16x16x32_bf16(whh_f[kt + 1], bh1, b1, 0, 0, 0);
      }
      const float gi = a0[0] + a1[0] + b0[0] + b1[0] + bias[0];
      const float gf = a0[1] + a1[1] + b0[1] + b1[1] + bias[1];
      const float gg = a0[2] + a1[2] + b0[2] + b1[2] + bias[2];
      const float go_ = a0[3] + a1[3] + b0[3] + b1[3] + bias[3];
      cn = sigf(gf) * c_cur + sigf(gi) * mytanh(gg);
      hn = sigf(go_) * mytanh(cn);
      c_cur = cn;

      // pack 4 cols (lhi 0..3, same sample) -> 8B agent store into hist slot t
      const u32 hu = (u32)f2bf(hn);
      const u32 pair = hu | (__shfl_xor(hu, 16) << 16);
      const u32 hi2 = __shfl_xor(pair, 32);
      if (lhi == 0) {
        const int slotW = histok ? t : (t & 1);
        const u64 v8 = (u64)pair | ((u64)hi2 << 32);
        u16* wp = hist + ((size_t)slotW * 2 + layer) * BnHn + (size_t)sampE * Hn + cc * 16 + mt * 4;
        __hip_atomic_store((u64*)wp, v8, __ATOMIC_RELAXED, __HIP_MEMORY_SCOPE_AGENT);
      }
    }
    // drain h stores, join WG, signal own slot (R9-proven producer protocol)
    asm volatile("s_waitcnt vmcnt(0)" ::: "memory");
    __syncthreads();
    ++ep;
    if (tid == 0)
      __hip_atomic_store(&slots[wg * 16], ep, __ATOMIC_RELAXED, __HIP_MEMORY_SCOPE_AGENT);

    // ---- shadow work (off the inter-WG critical path) ----
    if (act) {
      if (layer == 1)
        out[((size_t)t * Bn + sampE) * Hn + colE] = hn;
      if (t == Tn - 1) {
        out[(size_t)Tn * Bn * Hn + ((size_t)layer * Bn + sampE) * Hn + colE] = hn;
        out[(size_t)Tn * Bn * Hn + (size_t)2 * Bn * Hn + ((size_t)layer * Bn + sampE) * Hn + colE] = cn;
      }
    }
    if (layer == 0 && (s + 1) < Tn) stage_x(s + 1);

    if (s == Tn) break;   // nobody depends on the final barrier

    // ---- per-half two-level barrier (R9 topology, hot polls, LDS fanout) ----
    if (wave == 0) {
      if (leader_wg) {
        const int pid = (lane < 32) ? (shalf * 32 + lane)
                                    : (64 + shalf * 32 + (lane - 32));
        const u32* pl = &slots[pid * 16];
        while (true) {
          const u32 v = __hip_atomic_load(pl, __ATOMIC_RELAXED, __HIP_MEMORY_SCOPE_AGENT);
          if (__all((int)(v >= ep))) break;
        }
        __hip_atomic_store(&gof[pid * 16], ep, __ATOMIC_RELAXED, __HIP_MEMORY_SCOPE_AGENT);
      } else {
        while (__hip_atomic_load(&gof[wg * 16], __ATOMIC_RELAXED,
                                 __HIP_MEMORY_SCOPE_AGENT) < ep) {}
      }
      __hip_atomic_store(&sh_flag, ep, __ATOMIC_RELAXED, __HIP_MEMORY_SCOPE_WORKGROUP);
    } else {
      while (__hip_atomic_load(&sh_flag, __ATOMIC_RELAXED, __HIP_MEMORY_SCOPE_WORKGROUP) < ep) {}
    }
    asm volatile("" ::: "memory");   // keep data loads after the poll
  }
}

extern "C" void kernel_launch(void* const* d_in, const int* in_sizes, int n_in,
                              void* d_out, int out_size, void* d_ws, size_t ws_size,
                              hipStream_t stream) {
  const float* x   = (const float*)d_in[0];
  const float* hx  = (const float*)d_in[1];
  const float* cx  = (const float*)d_in[2];
  const float* Wih = (const float*)d_in[3];
  const float* Whh = (const float*)d_in[4];
  const float* bih = (const float*)d_in[5];
  const float* bhh = (const float*)d_in[6];
  float* outp = (float*)d_out;
  u32* wsp = (u32*)d_ws;

  const size_t slot_bytes = (size_t)2 * Bn * Hn * 2;            // 128KB per t-slot
  const size_t hist_bytes = (size_t)513 * slot_bytes;           // 67.2MB
  int histok = (ws_size >= HIST_OFF + hist_bytes) ? 1 : 0;
  const size_t xoff = HIST_OFF + (size_t)(histok ? 513 : 2) * slot_bytes;
  int xok = (ws_size >= xoff + (size_t)Tn * Bn * Hn * 2) ? 1 : 0;

  hipMemsetAsync(d_ws, 0, HIST_OFF, stream);   // zero slot + go lines every call

  lstm_prep<<<dim3(2048), dim3(256), 0, stream>>>(x, hx, wsp, xok, histok);

  void* args[] = {(void*)&x, (void*)&hx, (void*)&cx, (void*)&Wih, (void*)&Whh,
                  (void*)&bih, (void*)&bhh, (void*)&outp, (void*)&wsp,
                  (void*)&xok, (void*)&histok};
  hipError_t e = hipLaunchCooperativeKernel((const void*)lstm_fused, dim3(NWG),
                                            dim3(NTHR), args, 0, stream);
  if (e != hipSuccess) {
    lstm_fused<<<dim3(NWG), dim3(NTHR), 0, stream>>>(x, hx, cx, Wih, Whh, bih, bhh,
                                                     outp, wsp, xok, histok);
  }
}

// Round 16
// 1928.273 us; speedup vs baseline: 2.2709x; 1.0903x over previous
//
#include <hip/hip_runtime.h>
#include <hip/hip_bf16.h>
#include <stdint.h>

#define Tn 512
#define Bn 64
#define Hn 512
#define LDP 520           // LDS row pitch (u16): 1040B
#define NWG 128
#define NTHR 512
#define BnHn (Bn * Hn)

typedef unsigned short u16;
typedef unsigned int u32;
typedef unsigned long long u64;
typedef __attribute__((ext_vector_type(8))) short bf16x8;
typedef __attribute__((ext_vector_type(4))) float f32x4;

// ws layout (bytes):
//   0     : slots[128] (one 64B line per WG)   8KB
//   16384 : hist [nslot][2 layer][Bn][Hn] bf16  (nslot = 513 if histok else 4)
//   after : xbf [Tn][Bn][Hn] bf16 (32MB), if xok
#define HIST_OFF 16384

__device__ __forceinline__ u16 f2bf(float f) {
  u32 u = __float_as_uint(f);
  u = (u + 0x7FFFu + ((u >> 16) & 1u)) >> 16;   // RNE
  return (u16)u;
}
__device__ __forceinline__ float sigf(float x) { return 1.f / (1.f + __expf(-x)); }
__device__ __forceinline__ float mytanh(float x) {
  float e = __expf(2.f * x);
  return 1.f - 2.f / (e + 1.f);
}
__device__ __forceinline__ u32 ald32(const u32* p) {
  return __hip_atomic_load(p, __ATOMIC_RELAXED, __HIP_MEMORY_SCOPE_AGENT);
}

// ---------- pre-kernel: x -> bf16, hx -> hist init slot ----------
extern "C" __global__ void __launch_bounds__(256)
lstm_prep(const float* __restrict__ x, const float* __restrict__ hx,
          u32* __restrict__ ws, int xok, int histok) {
  u16* hist = (u16*)((char*)ws + HIST_OFF);
  u16* xbf  = hist + (size_t)(histok ? 513 : 4) * 2 * BnHn;
  const int slot_init = histok ? 512 : 3;
  const int gt = blockIdx.x * 256 + threadIdx.x;   // 0..524287
  if (xok) {
#pragma unroll
    for (int i = 0; i < 8; ++i) {
      const int c = gt + (i << 19);                // float4 chunk id, 4194304 total
      const float4 v = *(const float4*)(x + (size_t)c * 4);
      const u64 pk = (u64)((u32)f2bf(v.x) | ((u32)f2bf(v.y) << 16)) |
                     ((u64)((u32)f2bf(v.z) | ((u32)f2bf(v.w) << 16)) << 32);
      *(u64*)(xbf + (size_t)c * 4) = pk;
    }
  }
  if (gt < 32768) {
    const int e0 = 2 * gt;
    const int l = e0 >> 15;
    const int off = e0 & 32767;
    const u32 pk = (u32)f2bf(hx[e0]) | ((u32)f2bf(hx[e0 + 1]) << 16);
    *(u32*)(hist + ((size_t)slot_init * 2 + l) * BnHn + off) = pk;
  }
}

// ---------- main persistent cooperative kernel ----------
extern "C" __global__ void __launch_bounds__(NTHR, 2)
lstm_fused(const float* __restrict__ x, const float* __restrict__ hx,
           const float* __restrict__ cx, const float* __restrict__ Wih,
           const float* __restrict__ Whh, const float* __restrict__ bih,
           const float* __restrict__ bhh, float* __restrict__ out,
           u32* __restrict__ ws, int xok, int histok) {
  __shared__ u16 sh_inp[32 * LDP];
  __shared__ u16 sh_h[32 * LDP];

  // one-time L1/L2 invalidate: drop lines poisoned (0xAA) between launches
  __builtin_amdgcn_fence(__ATOMIC_ACQUIRE, "agent");

  const int wg = blockIdx.x;
  const int tid = threadIdx.x;
  const int layer = wg >> 6;        // 0..1
  const int rem = wg & 63;
  const int shalf = rem >> 5;       // batch half: samples 0-31 / 32-63
  const int cc = rem & 31;          // 16-column chunk
  const int wave = tid >> 6;        // 0..7
  const int lane = tid & 63;
  const int l15 = lane & 15;
  const int lhi = lane >> 4;
  const int mt = wave >> 1;         // 0..3 gate-row tile
  const int nt = wave & 1;          // 0..1 sample tile

  u32* slots = ws;                                   // slot[w] = slots[w*16]
  u16* hist  = (u16*)((char*)ws + HIST_OFF);
  u16* xbf   = hist + (size_t)(histok ? 513 : 4) * 2 * BnHn;
  const int init_slot = histok ? 512 : 3;

  // ---- weights -> registers. WG rows (64): j = col*4 + gate, col base cc*16 ----
  const int jrow = mt * 16 + l15;
  const int gateA = jrow & 3, colA = jrow >> 2;
  const int growA = gateA * Hn + cc * 16 + colA;
  const float* wihp = Wih + ((size_t)layer * 4 * Hn + growA) * Hn;
  const float* whhp = Whh + ((size_t)layer * 4 * Hn + growA) * Hn;
  bf16x8 wih_f[16], whh_f[16];
#pragma unroll
  for (int kt = 0; kt < 16; ++kt) {
    const int k0 = kt * 32 + lhi * 8;
    const float4 va0 = *(const float4*)(wihp + k0);
    const float4 va1 = *(const float4*)(wihp + k0 + 4);
    const float4 vb0 = *(const float4*)(whhp + k0);
    const float4 vb1 = *(const float4*)(whhp + k0 + 4);
    bf16x8 a, b;
    a[0]=(short)f2bf(va0.x); a[1]=(short)f2bf(va0.y); a[2]=(short)f2bf(va0.z); a[3]=(short)f2bf(va0.w);
    a[4]=(short)f2bf(va1.x); a[5]=(short)f2bf(va1.y); a[6]=(short)f2bf(va1.z); a[7]=(short)f2bf(va1.w);
    b[0]=(short)f2bf(vb0.x); b[1]=(short)f2bf(vb0.y); b[2]=(short)f2bf(vb0.z); b[3]=(short)f2bf(vb0.w);
    b[4]=(short)f2bf(vb1.x); b[5]=(short)f2bf(vb1.y); b[6]=(short)f2bf(vb1.z); b[7]=(short)f2bf(vb1.w);
    wih_f[kt] = a; whh_f[kt] = b;
  }

  // ---- elementwise lane mapping: acc reg r == gate r for (sampE, colE) ----
  const int colE = cc * 16 + mt * 4 + lhi;
  const int sampE = shalf * 32 + nt * 16 + l15;
  float bias[4];
#pragma unroll
  for (int r = 0; r < 4; ++r) {
    const int grow = r * Hn + cc * 16 + mt * 4 + lhi;
    bias[r] = bih[layer * 4 * Hn + grow] + bhh[layer * 4 * Hn + grow];
  }
  float c_cur = cx[((size_t)layer * Bn + sampE) * Hn + colE];

  // ---- flat-poll lane mapping: own group (lanes 0-31) + cross group (32-63) ----
  // L1 lags 2 steps -> cross RAW (L1 polls L0) has one-period slack (tgtoff=1).
  // histok: L0 has NO cross edge (monotonic hist = no WAR) -> duplicate own.
  // fallback 4-ring: L0 must throttle on L1's consumption (WAR) -> cross tgtoff=1.
  int pid, tgtoff;
  if (layer == 0) {
    if (lane < 32) { pid = shalf * 32 + lane; tgtoff = 0; }
    else if (histok) { pid = shalf * 32 + (lane - 32); tgtoff = 0; }
    else { pid = 64 + shalf * 32 + (lane - 32); tgtoff = 1; }
  } else {
    if (lane < 32) { pid = 64 + shalf * 32 + lane; tgtoff = 0; }
    else { pid = shalf * 32 + (lane - 32); tgtoff = 1; }
  }
  const u32* pollp = &slots[pid * 16];

  // stage x(t) -> sh_inp (layer 0); plain loads, coherent via prep boundary
  auto stage_x = [&](int t) {
    if (xok) {
      const u16* ip = xbf + ((size_t)t * Bn + shalf * 32) * Hn;
#pragma unroll
      for (int i = 0; i < 4; ++i) {
        const int chunk = tid + i * 512;             // 2048 chunks of 8 bf16
        const int row = chunk >> 6, c0 = (chunk & 63) * 8;
        const uint4 v = *(const uint4*)(ip + (size_t)row * Hn + c0);
        *(uint4*)(&sh_inp[row * LDP + c0]) = v;
      }
    } else {
      const float* xp = x + ((size_t)t * Bn + shalf * 32) * Hn;
#pragma unroll
      for (int i = 0; i < 8; ++i) {
        const int chunk = tid + i * 512;             // 4096 chunks of 4 floats
        const int row = chunk >> 7, c0 = (chunk & 127) * 4;
        const float4 v = *(const float4*)(xp + (size_t)row * Hn + c0);
        const u32 p0 = (u32)f2bf(v.x) | ((u32)f2bf(v.y) << 16);
        const u32 p1 = (u32)f2bf(v.z) | ((u32)f2bf(v.w) << 16);
        *(uint2*)(&sh_inp[row * LDP + c0]) = make_uint2(p0, p1);
      }
    }
  };
  // stage hist plane (slot, srclayer) -> LDS buffer
  auto stage_h = [&](int slot, int srclayer, u16* dst) {
    const u16* hp = hist + ((size_t)slot * 2 + srclayer) * BnHn + (size_t)(shalf * 32) * Hn;
    if (histok) {
#pragma unroll
      for (int i = 0; i < 4; ++i) {
        const int chunk = tid + i * 512;             // 2048 chunks of 16B (L2-cacheable)
        const int row = chunk >> 6, c0 = (chunk & 63) * 8;
        const uint4 v = *(const uint4*)(hp + (size_t)row * Hn + c0);
        *(uint4*)(&dst[row * LDP + c0]) = v;
      }
    } else {
#pragma unroll
      for (int i = 0; i < 8; ++i) {
        const int chunk = tid + i * 512;             // 4096 chunks of 8B (LLC-direct)
        const int row = chunk >> 7, c0 = (chunk & 127) * 4;
        const u64 v = __hip_atomic_load((const u64*)(hp + (size_t)row * Hn + c0),
                                        __ATOMIC_RELAXED, __HIP_MEMORY_SCOPE_AGENT);
        *(u64*)(&dst[row * LDP + c0]) = v;
      }
    }
  };
  if (layer == 0) stage_x(0);

  const int smax = Tn + 1;           // uniform loop; L1 lags 2 (t = s-2)
  u32 ep = 0;
  for (int s = 0; s <= smax; ++s) {
    const int t = layer ? s - 2 : s;
    const bool act = (t >= 0) && (t < Tn);

    if (act) {
      // own-layer recurrent h(t-1)
      const int slotR = (t == 0) ? init_slot : (histok ? (t - 1) : ((t - 1) & 3));
      stage_h(slotR, layer, sh_h);
      // L1 input: h0(t) (published 1 period ago thanks to lag-2)
      if (layer == 1) {
        const int slotI = histok ? t : (t & 3);
        stage_h(slotI, 0, sh_inp);
      }
    }
    __syncthreads();

    float hn = 0.f, cn = 0.f;
    if (act) {
      f32x4 a0 = {0,0,0,0}, a1 = {0,0,0,0}, b0 = {0,0,0,0}, b1 = {0,0,0,0};
      const int brow = (nt * 16 + l15) * LDP;
#pragma unroll
      for (int kt = 0; kt < 16; kt += 2) {
        const bf16x8 bi0 = *(const bf16x8*)(&sh_inp[brow + kt * 32 + lhi * 8]);
        const bf16x8 bh0 = *(const bf16x8*)(&sh_h[brow + kt * 32 + lhi * 8]);
        const bf16x8 bi1 = *(const bf16x8*)(&sh_inp[brow + (kt + 1) * 32 + lhi * 8]);
        const bf16x8 bh1 = *(const bf16x8*)(&sh_h[brow + (kt + 1) * 32 + lhi * 8]);
        a0 = __builtin_amdgcn_mfma_f32_16x16x32_bf16(wih_f[kt], bi0, a0, 0, 0, 0);
        b0 = __builtin_amdgcn_mfma_f32_16x16x32_bf16(whh_f[kt], bh0, b0, 0, 0, 0);
        a1 = __builtin_amdgcn_mfma_f32_16x16x32_bf16(wih_f[kt + 1], bi1, a1, 0, 0, 0);
        b1 = __builtin_amdgcn_mfma_f32_16x16x32_bf16(whh_f[kt + 1], bh1, b1, 0, 0, 0);
      }
      const float gi = a0[0] + a1[0] + b0[0] + b1[0] + bias[0];
      const float gf = a0[1] + a1[1] + b0[1] + b1[1] + bias[1];
      const float gg = a0[2] + a1[2] + b0[2] + b1[2] + bias[2];
      const float go_ = a0[3] + a1[3] + b0[3] + b1[3] + bias[3];
      cn = sigf(gf) * c_cur + sigf(gi) * mytanh(gg);
      hn = sigf(go_) * mytanh(cn);
      c_cur = cn;

      // pack 4 cols (lhi 0..3, same sample) -> 8B agent store into hist slot(t)
      const u32 hu = (u32)f2bf(hn);
      const u32 pair = hu | (__shfl_xor(hu, 16) << 16);
      const u32 hi2 = __shfl_xor(pair, 32);
      if (lhi == 0) {
        const int slotW = histok ? t : (t & 3);
        const u64 v8 = (u64)pair | ((u64)hi2 << 32);
        u16* wp = hist + ((size_t)slotW * 2 + layer) * BnHn + (size_t)sampE * Hn + cc * 16 + mt * 4;
        __hip_atomic_store((u64*)wp, v8, __ATOMIC_RELAXED, __HIP_MEMORY_SCOPE_AGENT);
      }
    }
    // drain h stores, join WG, signal own arrive line (relaxed; R9/R15-proven)
    asm volatile("s_waitcnt vmcnt(0)" ::: "memory");
    __syncthreads();
    ++ep;
    if (tid == 0)
      __hip_atomic_store(&slots[wg * 16], ep, __ATOMIC_RELAXED, __HIP_MEMORY_SCOPE_AGENT);

    // ---- shadow work (off the inter-WG critical path) ----
    if (act) {
      if (layer == 1)
        out[((size_t)t * Bn + sampE) * Hn + colE] = hn;
      if (t == Tn - 1) {
        out[(size_t)Tn * Bn * Hn + ((size_t)layer * Bn + sampE) * Hn + colE] = hn;
        out[(size_t)Tn * Bn * Hn + (size_t)2 * Bn * Hn + ((size_t)layer * Bn + sampE) * Hn + colE] = cn;
      }
    }
    if (layer == 0 && (s + 1) < Tn) stage_x(s + 1);

    if (s == smax) break;   // nobody depends on the final barrier

    // ---- flat single-hop group barrier: wave0 hot-polls 32(+32) lines ----
    if (wave == 0) {
      while (true) {
        const u32 v = ald32(pollp);
        if (__all((int)(v + (u32)tgtoff >= ep))) break;
      }
    }
    __syncthreads();   // join all waves to the detected epoch
    asm volatile("" ::: "memory");   // keep next restage loads after the poll
  }
}

extern "C" void kernel_launch(void* const* d_in, const int* in_sizes, int n_in,
                              void* d_out, int out_size, void* d_ws, size_t ws_size,
                              hipStream_t stream) {
  const float* x   = (const float*)d_in[0];
  const float* hx  = (const float*)d_in[1];
  const float* cx  = (const float*)d_in[2];
  const float* Wih = (const float*)d_in[3];
  const float* Whh = (const float*)d_in[4];
  const float* bih = (const float*)d_in[5];
  const float* bhh = (const float*)d_in[6];
  float* outp = (float*)d_out;
  u32* wsp = (u32*)d_ws;

  const size_t slot_bytes = (size_t)2 * Bn * Hn * 2;            // 128KB per t-slot
  int histok = (ws_size >= HIST_OFF + (size_t)513 * slot_bytes) ? 1 : 0;
  const size_t xoff = HIST_OFF + (size_t)(histok ? 513 : 4) * slot_bytes;
  int xok = (ws_size >= xoff + (size_t)Tn * Bn * Hn * 2) ? 1 : 0;

  hipMemsetAsync(d_ws, 0, HIST_OFF, stream);   // zero arrive lines every call

  lstm_prep<<<dim3(2048), dim3(256), 0, stream>>>(x, hx, wsp, xok, histok);

  void* args[] = {(void*)&x, (void*)&hx, (void*)&cx, (void*)&Wih, (void*)&Whh,
                  (void*)&bih, (void*)&bhh, (void*)&outp, (void*)&wsp,
                  (void*)&xok, (void*)&histok};
  hipError_t e = hipLaunchCooperativeKernel((const void*)lstm_fused, dim3(NWG),
                                            dim3(NTHR), args, 0, stream);
  if (e != hipSuccess) {
    lstm_fused<<<dim3(NWG), dim3(NTHR), 0, stream>>>(x, hx, cx, Wih, Whh, bih, bhh,
                                                     outp, wsp, xok, histok);
  }
}

// Round 17
// 1785.458 us; speedup vs baseline: 2.4526x; 1.0800x over previous
//
#include <hip/hip_runtime.h>
#include <hip/hip_bf16.h>
#include <stdint.h>

#define Tn 512
#define Bn 64
#define Hn 512
#define LDP 520           // LDS row pitch (u16): 1040B
#define NWG 128
#define NTHR 512
#define BnHn (Bn * Hn)

typedef unsigned short u16;
typedef unsigned int u32;
typedef unsigned long long u64;
typedef __attribute__((ext_vector_type(8))) short bf16x8;
typedef __attribute__((ext_vector_type(4))) float f32x4;

// ws layout (bytes):
//   0     : slots[128] (one 64B line per WG)   8KB
//   16384 : hist [nslot][2 layer][Bn][Hn] bf16  (nslot = 513 if histok else 8)
//   after : xbf [Tn][Bn][Hn] bf16 (32MB), if xok
#define HIST_OFF 16384

__device__ __forceinline__ u16 f2bf(float f) {
  u32 u = __float_as_uint(f);
  u = (u + 0x7FFFu + ((u >> 16) & 1u)) >> 16;   // RNE
  return (u16)u;
}
__device__ __forceinline__ float sigf(float x) { return 1.f / (1.f + __expf(-x)); }
__device__ __forceinline__ float mytanh(float x) {
  float e = __expf(2.f * x);
  return 1.f - 2.f / (e + 1.f);
}
__device__ __forceinline__ u32 ald32(const u32* p) {
  return __hip_atomic_load(p, __ATOMIC_RELAXED, __HIP_MEMORY_SCOPE_AGENT);
}

// ---------- pre-kernel: x -> bf16, hx -> hist init slot ----------
extern "C" __global__ void __launch_bounds__(256)
lstm_prep(const float* __restrict__ x, const float* __restrict__ hx,
          u32* __restrict__ ws, int xok, int histok) {
  u16* hist = (u16*)((char*)ws + HIST_OFF);
  u16* xbf  = hist + (size_t)(histok ? 513 : 8) * 2 * BnHn;
  const int slot_init = histok ? 512 : 7;
  const int gt = blockIdx.x * 256 + threadIdx.x;   // 0..524287
  if (xok) {
#pragma unroll
    for (int i = 0; i < 8; ++i) {
      const int c = gt + (i << 19);                // float4 chunk id, 4194304 total
      const float4 v = *(const float4*)(x + (size_t)c * 4);
      const u64 pk = (u64)((u32)f2bf(v.x) | ((u32)f2bf(v.y) << 16)) |
                     ((u64)((u32)f2bf(v.z) | ((u32)f2bf(v.w) << 16)) << 32);
      *(u64*)(xbf + (size_t)c * 4) = pk;
    }
  }
  if (gt < 32768) {
    const int e0 = 2 * gt;
    const int l = e0 >> 15;
    const int off = e0 & 32767;
    const u32 pk = (u32)f2bf(hx[e0]) | ((u32)f2bf(hx[e0 + 1]) << 16);
    *(u32*)(hist + ((size_t)slot_init * 2 + l) * BnHn + off) = pk;
  }
}

// ---------- main persistent cooperative kernel ----------
extern "C" __global__ void __launch_bounds__(NTHR, 2)
lstm_fused(const float* __restrict__ x, const float* __restrict__ hx,
           const float* __restrict__ cx, const float* __restrict__ Wih,
           const float* __restrict__ Whh, const float* __restrict__ bih,
           const float* __restrict__ bhh, float* __restrict__ out,
           u32* __restrict__ ws, int xok, int histok) {
  __shared__ u16 sh_inp[32 * LDP];
  __shared__ u16 sh_h[32 * LDP];

  // one-time L1/L2 invalidate: drop lines poisoned (0xAA) between launches
  __builtin_amdgcn_fence(__ATOMIC_ACQUIRE, "agent");

  const int wg = blockIdx.x;
  const int tid = threadIdx.x;
  const int layer = wg >> 6;        // 0..1
  const int rem = wg & 63;
  const int shalf = rem >> 5;       // batch half: samples 0-31 / 32-63
  const int cc = rem & 31;          // 16-column chunk
  const int wave = tid >> 6;        // 0..7
  const int lane = tid & 63;
  const int l15 = lane & 15;
  const int lhi = lane >> 4;
  const int mt = wave >> 1;         // 0..3 gate-row tile
  const int nt = wave & 1;          // 0..1 sample tile

  u32* slots = ws;                                   // slot[w] = slots[w*16]
  u16* hist  = (u16*)((char*)ws + HIST_OFF);
  u16* xbf   = hist + (size_t)(histok ? 513 : 8) * 2 * BnHn;
  const int init_slot = histok ? 512 : 7;

  // ---- weights -> registers. WG rows (64): j = col*4 + gate, col base cc*16 ----
  const int jrow = mt * 16 + l15;
  const int gateA = jrow & 3, colA = jrow >> 2;
  const int growA = gateA * Hn + cc * 16 + colA;
  const float* wihp = Wih + ((size_t)layer * 4 * Hn + growA) * Hn;
  const float* whhp = Whh + ((size_t)layer * 4 * Hn + growA) * Hn;
  bf16x8 wih_f[16], whh_f[16];
#pragma unroll
  for (int kt = 0; kt < 16; ++kt) {
    const int k0 = kt * 32 + lhi * 8;
    const float4 va0 = *(const float4*)(wihp + k0);
    const float4 va1 = *(const float4*)(wihp + k0 + 4);
    const float4 vb0 = *(const float4*)(whhp + k0);
    const float4 vb1 = *(const float4*)(whhp + k0 + 4);
    bf16x8 a, b;
    a[0]=(short)f2bf(va0.x); a[1]=(short)f2bf(va0.y); a[2]=(short)f2bf(va0.z); a[3]=(short)f2bf(va0.w);
    a[4]=(short)f2bf(va1.x); a[5]=(short)f2bf(va1.y); a[6]=(short)f2bf(va1.z); a[7]=(short)f2bf(va1.w);
    b[0]=(short)f2bf(vb0.x); b[1]=(short)f2bf(vb0.y); b[2]=(short)f2bf(vb0.z); b[3]=(short)f2bf(vb0.w);
    b[4]=(short)f2bf(vb1.x); b[5]=(short)f2bf(vb1.y); b[6]=(short)f2bf(vb1.z); b[7]=(short)f2bf(vb1.w);
    wih_f[kt] = a; whh_f[kt] = b;
  }

  // ---- elementwise lane mapping: acc reg r == gate r for (sampE, colE) ----
  const int colE = cc * 16 + mt * 4 + lhi;
  const int sampE = shalf * 32 + nt * 16 + l15;
  float bias[4];
#pragma unroll
  for (int r = 0; r < 4; ++r) {
    const int grow = r * Hn + cc * 16 + mt * 4 + lhi;
    bias[r] = bih[layer * 4 * Hn + grow] + bhh[layer * 4 * Hn + grow];
  }
  float c_cur = cx[((size_t)layer * Bn + sampE) * Hn + colE];

  // ---- flat-poll lane mapping (R16-proven): own group + cross group ----
  // L1 lags 3 -> cross RAW (L1 polls L0, tgtoff=1) guarantees h0(s-2) drained
  // at end of loop s-1 (v >= s-1  <=>  L0 completed step s-2).
  // histok: L0 has NO cross edge (monotonic hist = no WAR) -> duplicate own.
  // fallback 8-ring: L0 throttles on L1 consumption (tgtoff=1; 8 slots cover lag-3).
  int pid, tgtoff;
  if (layer == 0) {
    if (lane < 32) { pid = shalf * 32 + lane; tgtoff = 0; }
    else if (histok) { pid = shalf * 32 + (lane - 32); tgtoff = 0; }
    else { pid = 64 + shalf * 32 + (lane - 32); tgtoff = 1; }
  } else {
    if (lane < 32) { pid = 64 + shalf * 32 + lane; tgtoff = 0; }
    else { pid = shalf * 32 + (lane - 32); tgtoff = 1; }
  }
  const u32* pollp = &slots[pid * 16];

  // stage x(t) -> sh_inp (layer 0); plain loads, coherent via prep boundary
  auto stage_x = [&](int t) {
    if (xok) {
      const u16* ip = xbf + ((size_t)t * Bn + shalf * 32) * Hn;
#pragma unroll
      for (int i = 0; i < 4; ++i) {
        const int chunk = tid + i * 512;             // 2048 chunks of 8 bf16
        const int row = chunk >> 6, c0 = (chunk & 63) * 8;
        const uint4 v = *(const uint4*)(ip + (size_t)row * Hn + c0);
        *(uint4*)(&sh_inp[row * LDP + c0]) = v;
      }
    } else {
      const float* xp = x + ((size_t)t * Bn + shalf * 32) * Hn;
#pragma unroll
      for (int i = 0; i < 8; ++i) {
        const int chunk = tid + i * 512;             // 4096 chunks of 4 floats
        const int row = chunk >> 7, c0 = (chunk & 127) * 4;
        const float4 v = *(const float4*)(xp + (size_t)row * Hn + c0);
        const u32 p0 = (u32)f2bf(v.x) | ((u32)f2bf(v.y) << 16);
        const u32 p1 = (u32)f2bf(v.z) | ((u32)f2bf(v.w) << 16);
        *(uint2*)(&sh_inp[row * LDP + c0]) = make_uint2(p0, p1);
      }
    }
  };
  // stage hist plane (slot, srclayer) -> LDS buffer
  auto stage_h = [&](int slot, int srclayer, u16* dst) {
    const u16* hp = hist + ((size_t)slot * 2 + srclayer) * BnHn + (size_t)(shalf * 32) * Hn;
    if (histok) {
#pragma unroll
      for (int i = 0; i < 4; ++i) {
        const int chunk = tid + i * 512;             // 2048 chunks of 16B (L2-cacheable)
        const int row = chunk >> 6, c0 = (chunk & 63) * 8;
        const uint4 v = *(const uint4*)(hp + (size_t)row * Hn + c0);
        *(uint4*)(&dst[row * LDP + c0]) = v;
      }
    } else {
#pragma unroll
      for (int i = 0; i < 8; ++i) {
        const int chunk = tid + i * 512;             // 4096 chunks of 8B (LLC-direct)
        const int row = chunk >> 7, c0 = (chunk & 127) * 4;
        const u64 v = __hip_atomic_load((const u64*)(hp + (size_t)row * Hn + c0),
                                        __ATOMIC_RELAXED, __HIP_MEMORY_SCOPE_AGENT);
        *(u64*)(&dst[row * LDP + c0]) = v;
      }
    }
  };
  // ih-GEMM from sh_inp into persistent accumulators (shadow-phase compute)
  f32x4 aI0 = {0.f,0.f,0.f,0.f}, aI1 = {0.f,0.f,0.f,0.f};
  auto compute_aI = [&]() {
    f32x4 t0 = {0.f,0.f,0.f,0.f}, t1 = {0.f,0.f,0.f,0.f};
    const int brow = (nt * 16 + l15) * LDP;
#pragma unroll
    for (int kt = 0; kt < 16; kt += 2) {
      const bf16x8 bi0 = *(const bf16x8*)(&sh_inp[brow + kt * 32 + lhi * 8]);
      const bf16x8 bi1 = *(const bf16x8*)(&sh_inp[brow + (kt + 1) * 32 + lhi * 8]);
      t0 = __builtin_amdgcn_mfma_f32_16x16x32_bf16(wih_f[kt], bi0, t0, 0, 0, 0);
      t1 = __builtin_amdgcn_mfma_f32_16x16x32_bf16(wih_f[kt + 1], bi1, t1, 0, 0, 0);
    }
    aI0 = t0; aI1 = t1;
  };

  // ---- pre-loop: L0 stages x(0) and precomputes aI(0) ----
  if (layer == 0) stage_x(0);
  __syncthreads();
  if (layer == 0) compute_aI();

  const int smax = Tn + 2;           // L1 lags 3 (t = s-3); L0 idles s >= Tn
  u32 ep = 0;
  for (int s = 0; s <= smax; ++s) {
    const int t = layer ? s - 3 : s;
    const bool act = (t >= 0) && (t < Tn);

    // ---------- critical phase: restage own h(t-1), hh-GEMM, elementwise ----------
    if (act) {
      const int slotR = (t == 0) ? init_slot : (histok ? (t - 1) : ((t - 1) & 7));
      stage_h(slotR, layer, sh_h);
    }
    __syncthreads();

    float hn = 0.f, cn = 0.f;
    if (act) {
      f32x4 b0 = {0,0,0,0}, b1 = {0,0,0,0};
      const int brow = (nt * 16 + l15) * LDP;
#pragma unroll
      for (int kt = 0; kt < 16; kt += 2) {
        const bf16x8 bh0 = *(const bf16x8*)(&sh_h[brow + kt * 32 + lhi * 8]);
        const bf16x8 bh1 = *(const bf16x8*)(&sh_h[brow + (kt + 1) * 32 + lhi * 8]);
        b0 = __builtin_amdgcn_mfma_f32_16x16x32_bf16(whh_f[kt], bh0, b0, 0, 0, 0);
        b1 = __builtin_amdgcn_mfma_f32_16x16x32_bf16(whh_f[kt + 1], bh1, b1, 0, 0, 0);
      }
      const float gi = aI0[0] + aI1[0] + b0[0] + b1[0] + bias[0];
      const float gf = aI0[1] + aI1[1] + b0[1] + b1[1] + bias[1];
      const float gg = aI0[2] + aI1[2] + b0[2] + b1[2] + bias[2];
      const float go_ = aI0[3] + aI1[3] + b0[3] + b1[3] + bias[3];
      cn = sigf(gf) * c_cur + sigf(gi) * mytanh(gg);
      hn = sigf(go_) * mytanh(cn);
      c_cur = cn;

      // pack 4 cols (lhi 0..3, same sample) -> 8B agent store into hist slot(t)
      const u32 hu = (u32)f2bf(hn);
      const u32 pair = hu | (__shfl_xor(hu, 16) << 16);
      const u32 hi2 = __shfl_xor(pair, 32);
      if (lhi == 0) {
        const int slotW = histok ? t : (t & 7);
        const u64 v8 = (u64)pair | ((u64)hi2 << 32);
        u16* wp = hist + ((size_t)slotW * 2 + layer) * BnHn + (size_t)sampE * Hn + cc * 16 + mt * 4;
        __hip_atomic_store((u64*)wp, v8, __ATOMIC_RELAXED, __HIP_MEMORY_SCOPE_AGENT);
      }
    }
    // drain h stores, join WG, signal own arrive line (relaxed; proven protocol)
    asm volatile("s_waitcnt vmcnt(0)" ::: "memory");
    __syncthreads();
    ++ep;
    if (tid == 0)
      __hip_atomic_store(&slots[wg * 16], ep, __ATOMIC_RELAXED, __HIP_MEMORY_SCOPE_AGENT);

    // ---------- shadow phase: outputs + next-step input staging + ih-GEMM ----------
    if (act) {
      if (layer == 1)
        out[((size_t)t * Bn + sampE) * Hn + colE] = hn;
      if (t == Tn - 1) {
        out[(size_t)Tn * Bn * Hn + ((size_t)layer * Bn + sampE) * Hn + colE] = hn;
        out[(size_t)Tn * Bn * Hn + (size_t)2 * Bn * Hn + ((size_t)layer * Bn + sampE) * Hn + colE] = cn;
      }
    }
    bool ihnext = false;
    if (layer == 0) {
      if (s + 1 < Tn) { stage_x(s + 1); ihnext = true; }
    } else {
      const int u = s - 2;           // next step's input h0(u); guaranteed drained
      if (u >= 0 && u < Tn) {        // by the tgtoff=1 cross-check at end of loop s-1
        const int slotI = histok ? u : (u & 7);
        stage_h(slotI, 0, sh_inp);
        ihnext = true;
      }
    }
    __syncthreads();                 // sh_inp staged before ih-GEMM reads
    if (ihnext) compute_aI();

    if (s == smax) break;            // nobody depends on the final barrier

    // ---- flat single-hop group barrier: wave0 hot-polls 32(+32) lines ----
    if (wave == 0) {
      while (true) {
        const u32 v = ald32(pollp);
        if (__all((int)(v + (u32)tgtoff >= ep))) break;
      }
    }
    __syncthreads();   // join all waves to the detected epoch
    asm volatile("" ::: "memory");   // keep next restage loads after the poll
  }
}

extern "C" void kernel_launch(void* const* d_in, const int* in_sizes, int n_in,
                              void* d_out, int out_size, void* d_ws, size_t ws_size,
                              hipStream_t stream) {
  const float* x   = (const float*)d_in[0];
  const float* hx  = (const float*)d_in[1];
  const float* cx  = (const float*)d_in[2];
  const float* Wih = (const float*)d_in[3];
  const float* Whh = (const float*)d_in[4];
  const float* bih = (const float*)d_in[5];
  const float* bhh = (const float*)d_in[6];
  float* outp = (float*)d_out;
  u32* wsp = (u32*)d_ws;

  const size_t slot_bytes = (size_t)2 * Bn * Hn * 2;            // 128KB per t-slot
  int histok = (ws_size >= HIST_OFF + (size_t)513 * slot_bytes) ? 1 : 0;
  const size_t xoff = HIST_OFF + (size_t)(histok ? 513 : 8) * slot_bytes;
  int xok = (ws_size >= xoff + (size_t)Tn * Bn * Hn * 2) ? 1 : 0;

  hipMemsetAsync(d_ws, 0, HIST_OFF, stream);   // zero arrive lines every call

  lstm_prep<<<dim3(2048), dim3(256), 0, stream>>>(x, hx, wsp, xok, histok);

  void* args[] = {(void*)&x, (void*)&hx, (void*)&cx, (void*)&Wih, (void*)&Whh,
                  (void*)&bih, (void*)&bhh, (void*)&outp, (void*)&wsp,
                  (void*)&xok, (void*)&histok};
  hipError_t e = hipLaunchCooperativeKernel((const void*)lstm_fused, dim3(NWG),
                                            dim3(NTHR), args, 0, stream);
  if (e != hipSuccess) {
    lstm_fused<<<dim3(NWG), dim3(NTHR), 0, stream>>>(x, hx, cx, Wih, Whh, bih, bhh,
                                                     outp, wsp, xok, histok);
  }
}

// Round 18
// 1748.338 us; speedup vs baseline: 2.5046x; 1.0212x over previous
//
#include <hip/hip_runtime.h>
#include <hip/hip_bf16.h>
#include <stdint.h>

#define Tn 512
#define Bn 64
#define Hn 512
#define LDP 520           // LDS row pitch (u16): 1040B
#define NWG 128
#define NTHR 512
#define BnHn (Bn * Hn)

typedef unsigned short u16;
typedef unsigned int u32;
typedef unsigned long long u64;
typedef __attribute__((ext_vector_type(8))) short bf16x8;
typedef __attribute__((ext_vector_type(4))) float f32x4;

// ws layout (bytes):
//   0     : flags[4 groups][32 cc] u32, 128B-aligned per group  (512B)
//   16384 : hist [nslot][2 layer][Bn][Hn] bf16  (nslot = 513 if histok else 8)
//   after : xbf [Tn][Bn][Hn] bf16 (32MB), if xok
#define HIST_OFF 16384

__device__ __forceinline__ u16 f2bf(float f) {
  u32 u = __float_as_uint(f);
  u = (u + 0x7FFFu + ((u >> 16) & 1u)) >> 16;   // RNE
  return (u16)u;
}
__device__ __forceinline__ float sigf(float x) { return 1.f / (1.f + __expf(-x)); }
__device__ __forceinline__ float mytanh(float x) {
  float e = __expf(2.f * x);
  return 1.f - 2.f / (e + 1.f);
}
__device__ __forceinline__ u32 ald32(const u32* p) {
  return __hip_atomic_load(p, __ATOMIC_RELAXED, __HIP_MEMORY_SCOPE_AGENT);
}

// ---------- pre-kernel: x -> bf16, hx -> hist init slot ----------
extern "C" __global__ void __launch_bounds__(256)
lstm_prep(const float* __restrict__ x, const float* __restrict__ hx,
          u32* __restrict__ ws, int xok, int histok) {
  u16* hist = (u16*)((char*)ws + HIST_OFF);
  u16* xbf  = hist + (size_t)(histok ? 513 : 8) * 2 * BnHn;
  const int slot_init = histok ? 512 : 7;
  const int gt = blockIdx.x * 256 + threadIdx.x;   // 0..524287
  if (xok) {
#pragma unroll
    for (int i = 0; i < 8; ++i) {
      const int c = gt + (i << 19);                // float4 chunk id, 4194304 total
      const float4 v = *(const float4*)(x + (size_t)c * 4);
      const u64 pk = (u64)((u32)f2bf(v.x) | ((u32)f2bf(v.y) << 16)) |
                     ((u64)((u32)f2bf(v.z) | ((u32)f2bf(v.w) << 16)) << 32);
      *(u64*)(xbf + (size_t)c * 4) = pk;
    }
  }
  if (gt < 32768) {
    const int e0 = 2 * gt;
    const int l = e0 >> 15;
    const int off = e0 & 32767;
    const u32 pk = (u32)f2bf(hx[e0]) | ((u32)f2bf(hx[e0 + 1]) << 16);
    *(u32*)(hist + ((size_t)slot_init * 2 + l) * BnHn + off) = pk;
  }
}

// ---------- main persistent cooperative kernel ----------
extern "C" __global__ void __launch_bounds__(NTHR, 2)
lstm_fused(const float* __restrict__ x, const float* __restrict__ hx,
           const float* __restrict__ cx, const float* __restrict__ Wih,
           const float* __restrict__ Whh, const float* __restrict__ bih,
           const float* __restrict__ bhh, float* __restrict__ out,
           u32* __restrict__ ws, int xok, int histok) {
  __shared__ u16 sh_inp[32 * LDP];
  __shared__ u16 sh_h[32 * LDP];

  // one-time L1/L2 invalidate: drop lines poisoned (0xAA) between launches
  __builtin_amdgcn_fence(__ATOMIC_ACQUIRE, "agent");

  const int wg = blockIdx.x;
  const int tid = threadIdx.x;
  const int layer = wg >> 6;        // 0..1
  const int rem = wg & 63;
  const int shalf = rem >> 5;       // batch half: samples 0-31 / 32-63
  const int cc = rem & 31;          // 16-column chunk
  const int wave = tid >> 6;        // 0..7
  const int lane = tid & 63;
  const int l15 = lane & 15;
  const int lhi = lane >> 4;
  const int mt = wave >> 1;         // 0..3 gate-row tile
  const int nt = wave & 1;          // 0..1 sample tile

  u32* flags = ws;                  // flags[g*32 + cc], 128B-aligned per group
  u16* hist  = (u16*)((char*)ws + HIST_OFF);
  u16* xbf   = hist + (size_t)(histok ? 513 : 8) * 2 * BnHn;
  const int init_slot = histok ? 512 : 7;
  const int gid = layer * 2 + shalf;

  // ---- weights -> registers. WG rows (64): j = col*4 + gate, col base cc*16 ----
  const int jrow = mt * 16 + l15;
  const int gateA = jrow & 3, colA = jrow >> 2;
  const int growA = gateA * Hn + cc * 16 + colA;
  const float* wihp = Wih + ((size_t)layer * 4 * Hn + growA) * Hn;
  const float* whhp = Whh + ((size_t)layer * 4 * Hn + growA) * Hn;
  bf16x8 wih_f[16], whh_f[16];
#pragma unroll
  for (int kt = 0; kt < 16; ++kt) {
    const int k0 = kt * 32 + lhi * 8;
    const float4 va0 = *(const float4*)(wihp + k0);
    const float4 va1 = *(const float4*)(wihp + k0 + 4);
    const float4 vb0 = *(const float4*)(whhp + k0);
    const float4 vb1 = *(const float4*)(whhp + k0 + 4);
    bf16x8 a, b;
    a[0]=(short)f2bf(va0.x); a[1]=(short)f2bf(va0.y); a[2]=(short)f2bf(va0.z); a[3]=(short)f2bf(va0.w);
    a[4]=(short)f2bf(va1.x); a[5]=(short)f2bf(va1.y); a[6]=(short)f2bf(va1.z); a[7]=(short)f2bf(va1.w);
    b[0]=(short)f2bf(vb0.x); b[1]=(short)f2bf(vb0.y); b[2]=(short)f2bf(vb0.z); b[3]=(short)f2bf(vb0.w);
    b[4]=(short)f2bf(vb1.x); b[5]=(short)f2bf(vb1.y); b[6]=(short)f2bf(vb1.z); b[7]=(short)f2bf(vb1.w);
    wih_f[kt] = a; whh_f[kt] = b;
  }

  // ---- elementwise lane mapping: acc reg r == gate r for (sampE, colE) ----
  const int colE = cc * 16 + mt * 4 + lhi;
  const int sampE = shalf * 32 + nt * 16 + l15;
  float bias[4];
#pragma unroll
  for (int r = 0; r < 4; ++r) {
    const int grow = r * Hn + cc * 16 + mt * 4 + lhi;
    bias[r] = bih[layer * 4 * Hn + grow] + bhh[layer * 4 * Hn + grow];
  }
  float c_cur = cx[((size_t)layer * Bn + sampE) * Hn + colE];

  // ---- packed flat-poll lane mapping (edge semantics identical to R17) ----
  // L1 lags 3 -> cross RAW (L1 polls L0, tgtoff=1). histok: L0 has no cross
  // edge (monotonic hist) -> duplicate own. fallback 8-ring: L0 WAR tgtoff=1.
  int pidx, tgtoff;
  if (layer == 0) {
    if (lane < 32) { pidx = (0 * 2 + shalf) * 32 + lane; tgtoff = 0; }
    else if (histok) { pidx = (0 * 2 + shalf) * 32 + (lane - 32); tgtoff = 0; }
    else { pidx = (1 * 2 + shalf) * 32 + (lane - 32); tgtoff = 1; }
  } else {
    if (lane < 32) { pidx = (1 * 2 + shalf) * 32 + lane; tgtoff = 0; }
    else { pidx = (0 * 2 + shalf) * 32 + (lane - 32); tgtoff = 1; }
  }
  const u32* pollp = &flags[pidx];

  // stage x(t) -> sh_inp (layer 0); plain loads, coherent via prep boundary
  auto stage_x = [&](int t) {
    if (xok) {
      const u16* ip = xbf + ((size_t)t * Bn + shalf * 32) * Hn;
#pragma unroll
      for (int i = 0; i < 4; ++i) {
        const int chunk = tid + i * 512;             // 2048 chunks of 8 bf16
        const int row = chunk >> 6, c0 = (chunk & 63) * 8;
        const uint4 v = *(const uint4*)(ip + (size_t)row * Hn + c0);
        *(uint4*)(&sh_inp[row * LDP + c0]) = v;
      }
    } else {
      const float* xp = x + ((size_t)t * Bn + shalf * 32) * Hn;
#pragma unroll
      for (int i = 0; i < 8; ++i) {
        const int chunk = tid + i * 512;             // 4096 chunks of 4 floats
        const int row = chunk >> 7, c0 = (chunk & 127) * 4;
        const float4 v = *(const float4*)(xp + (size_t)row * Hn + c0);
        const u32 p0 = (u32)f2bf(v.x) | ((u32)f2bf(v.y) << 16);
        const u32 p1 = (u32)f2bf(v.z) | ((u32)f2bf(v.w) << 16);
        *(uint2*)(&sh_inp[row * LDP + c0]) = make_uint2(p0, p1);
      }
    }
  };
  // stage hist plane (slot, srclayer) -> LDS buffer
  auto stage_h = [&](int slot, int srclayer, u16* dst) {
    const u16* hp = hist + ((size_t)slot * 2 + srclayer) * BnHn + (size_t)(shalf * 32) * Hn;
    if (histok) {
#pragma unroll
      for (int i = 0; i < 4; ++i) {
        const int chunk = tid + i * 512;             // 2048 chunks of 16B (L2-cacheable)
        const int row = chunk >> 6, c0 = (chunk & 63) * 8;
        const uint4 v = *(const uint4*)(hp + (size_t)row * Hn + c0);
        *(uint4*)(&dst[row * LDP + c0]) = v;
      }
    } else {
#pragma unroll
      for (int i = 0; i < 8; ++i) {
        const int chunk = tid + i * 512;             // 4096 chunks of 8B (LLC-direct)
        const int row = chunk >> 7, c0 = (chunk & 127) * 4;
        const u64 v = __hip_atomic_load((const u64*)(hp + (size_t)row * Hn + c0),
                                        __ATOMIC_RELAXED, __HIP_MEMORY_SCOPE_AGENT);
        *(u64*)(&dst[row * LDP + c0]) = v;
      }
    }
  };
  // ih-GEMM from sh_inp into persistent accumulators (shadow-phase compute)
  f32x4 aI0 = {0.f,0.f,0.f,0.f}, aI1 = {0.f,0.f,0.f,0.f};
  auto compute_aI = [&]() {
    f32x4 t0 = {0.f,0.f,0.f,0.f}, t1 = {0.f,0.f,0.f,0.f};
    const int brow = (nt * 16 + l15) * LDP;
#pragma unroll
    for (int kt = 0; kt < 16; kt += 2) {
      const bf16x8 bi0 = *(const bf16x8*)(&sh_inp[brow + kt * 32 + lhi * 8]);
      const bf16x8 bi1 = *(const bf16x8*)(&sh_inp[brow + (kt + 1) * 32 + lhi * 8]);
      t0 = __builtin_amdgcn_mfma_f32_16x16x32_bf16(wih_f[kt], bi0, t0, 0, 0, 0);
      t1 = __builtin_amdgcn_mfma_f32_16x16x32_bf16(wih_f[kt + 1], bi1, t1, 0, 0, 0);
    }
    aI0 = t0; aI1 = t1;
  };

  // ---- pre-loop: L0 stages x(0) and precomputes aI(0) ----
  if (layer == 0) stage_x(0);
  __syncthreads();
  if (layer == 0) compute_aI();

  const int smax = Tn + 2;           // L1 lags 3 (t = s-3); L0 idles s >= Tn
  u32 ep = 0;
  for (int s = 0; s <= smax; ++s) {
    const int t = layer ? s - 3 : s;
    const bool act = (t >= 0) && (t < Tn);

    // ---------- critical phase: restage own h(t-1), hh-GEMM, elementwise ----------
    if (act) {
      const int slotR = (t == 0) ? init_slot : (histok ? (t - 1) : ((t - 1) & 7));
      stage_h(slotR, layer, sh_h);
    }
    __syncthreads();

    float hn = 0.f, cn = 0.f;
    if (act) {
      f32x4 b0 = {0,0,0,0}, b1 = {0,0,0,0};
      const int brow = (nt * 16 + l15) * LDP;
#pragma unroll
      for (int kt = 0; kt < 16; kt += 2) {
        const bf16x8 bh0 = *(const bf16x8*)(&sh_h[brow + kt * 32 + lhi * 8]);
        const bf16x8 bh1 = *(const bf16x8*)(&sh_h[brow + (kt + 1) * 32 + lhi * 8]);
        b0 = __builtin_amdgcn_mfma_f32_16x16x32_bf16(whh_f[kt], bh0, b0, 0, 0, 0);
        b1 = __builtin_amdgcn_mfma_f32_16x16x32_bf16(whh_f[kt + 1], bh1, b1, 0, 0, 0);
      }
      const float gi = aI0[0] + aI1[0] + b0[0] + b1[0] + bias[0];
      const float gf = aI0[1] + aI1[1] + b0[1] + b1[1] + bias[1];
      const float gg = aI0[2] + aI1[2] + b0[2] + b1[2] + bias[2];
      const float go_ = aI0[3] + aI1[3] + b0[3] + b1[3] + bias[3];
      cn = sigf(gf) * c_cur + sigf(gi) * mytanh(gg);
      hn = sigf(go_) * mytanh(cn);
      c_cur = cn;

      // pack 4 cols (lhi 0..3, same sample) -> 8B agent store into hist slot(t)
      const u32 hu = (u32)f2bf(hn);
      const u32 pair = hu | (__shfl_xor(hu, 16) << 16);
      const u32 hi2 = __shfl_xor(pair, 32);
      if (lhi == 0) {
        const int slotW = histok ? t : (t & 7);
        const u64 v8 = (u64)pair | ((u64)hi2 << 32);
        u16* wp = hist + ((size_t)slotW * 2 + layer) * BnHn + (size_t)sampE * Hn + cc * 16 + mt * 4;
        __hip_atomic_store((u64*)wp, v8, __ATOMIC_RELAXED, __HIP_MEMORY_SCOPE_AGENT);
      }
    }
    // drain h stores, join WG, signal own packed flag (relaxed; proven protocol)
    asm volatile("s_waitcnt vmcnt(0)" ::: "memory");
    __syncthreads();
    ++ep;
    if (tid == 0)
      __hip_atomic_store(&flags[gid * 32 + cc], ep,
                         __ATOMIC_RELAXED, __HIP_MEMORY_SCOPE_AGENT);

    // ---------- shadow phase: outputs + next-step input staging + ih-GEMM ----------
    if (act) {
      if (layer == 1)
        out[((size_t)t * Bn + sampE) * Hn + colE] = hn;
      if (t == Tn - 1) {
        out[(size_t)Tn * Bn * Hn + ((size_t)layer * Bn + sampE) * Hn + colE] = hn;
        out[(size_t)Tn * Bn * Hn + (size_t)2 * Bn * Hn + ((size_t)layer * Bn + sampE) * Hn + colE] = cn;
      }
    }
    bool ihnext = false;
    if (layer == 0) {
      if (s + 1 < Tn) { stage_x(s + 1); ihnext = true; }
    } else {
      const int u = s - 2;           // next step's input h0(u); guaranteed drained
      if (u >= 0 && u < Tn) {        // by the tgtoff=1 cross-check at end of loop s-1
        const int slotI = histok ? u : (u & 7);
        stage_h(slotI, 0, sh_inp);
        ihnext = true;
      }
    }
    __syncthreads();                 // sh_inp staged before ih-GEMM reads
    if (ihnext) compute_aI();

    if (s == smax) break;            // nobody depends on the final barrier

    // ---- packed flat barrier: ALL waves hot-poll 2-4 coalesced lines ----
    // Safe without a post-poll __syncthreads: every wave passed the pre-signal
    // __syncthreads (all sh_h reads done) before any wave can detect and begin
    // restage-writes; the post-restage __syncthreads re-joins before reads.
    while (true) {
      const u32 v = ald32(pollp);
      if (__all((int)(v + (u32)tgtoff >= ep))) break;
    }
    asm volatile("" ::: "memory");   // keep next restage loads after the poll
  }
}

extern "C" void kernel_launch(void* const* d_in, const int* in_sizes, int n_in,
                              void* d_out, int out_size, void* d_ws, size_t ws_size,
                              hipStream_t stream) {
  const float* x   = (const float*)d_in[0];
  const float* hx  = (const float*)d_in[1];
  const float* cx  = (const float*)d_in[2];
  const float* Wih = (const float*)d_in[3];
  const float* Whh = (const float*)d_in[4];
  const float* bih = (const float*)d_in[5];
  const float* bhh = (const float*)d_in[6];
  float* outp = (float*)d_out;
  u32* wsp = (u32*)d_ws;

  const size_t slot_bytes = (size_t)2 * Bn * Hn * 2;            // 128KB per t-slot
  int histok = (ws_size >= HIST_OFF + (size_t)513 * slot_bytes) ? 1 : 0;
  const size_t xoff = HIST_OFF + (size_t)(histok ? 513 : 8) * slot_bytes;
  int xok = (ws_size >= xoff + (size_t)Tn * Bn * Hn * 2) ? 1 : 0;

  hipMemsetAsync(d_ws, 0, HIST_OFF, stream);   // zero flag lines every call

  lstm_prep<<<dim3(2048), dim3(256), 0, stream>>>(x, hx, wsp, xok, histok);

  void* args[] = {(void*)&x, (void*)&hx, (void*)&cx, (void*)&Wih, (void*)&Whh,
                  (void*)&bih, (void*)&bhh, (void*)&outp, (void*)&wsp,
                  (void*)&xok, (void*)&histok};
  hipError_t e = hipLaunchCooperativeKernel((const void*)lstm_fused, dim3(NWG),
                                            dim3(NTHR), args, 0, stream);
  if (e != hipSuccess) {
    lstm_fused<<<dim3(NWG), dim3(NTHR), 0, stream>>>(x, hx, cx, Wih, Whh, bih, bhh,
                                                     outp, wsp, xok, histok);
  }
}